// Round 1
// baseline (4527.911 us; speedup 1.0000x reference)
//
#include <hip/hip_runtime.h>
#include <hip/hip_bf16.h>
#include <math.h>

#define B_   4
#define H_   8
#define NQ_  2048
#define NK_  2048
#define DM_  512
#define DK_  64

// ---------------------------------------------------------------------------
// GEMM: X (M x 512) @ W (512 x 512) + bias -> out
// MODE 0: out in (B, H, N, 64) layout (projection epilogue; one head per
//         64-wide N tile since TILE_N == 64 == D_K)
// MODE 1: plain row-major M x 512
// ---------------------------------------------------------------------------
template<int MODE>
__global__ __launch_bounds__(256) void gemm512(const float* __restrict__ A,
                                               const float* __restrict__ W,
                                               const float* __restrict__ bias,
                                               float* __restrict__ out)
{
    __shared__ float As[64][17];   // [m][k], pad 17 -> conflict-free scalar reads
    __shared__ float Bs[16][64];   // [k][n], float4 reads are 2-way (free)

    const int tid = threadIdx.x;
    const int tx = tid & 15, ty = tid >> 4;
    const int m0 = blockIdx.x * 64, n0 = blockIdx.y * 64;

    float acc[4][4] = {};

    for (int kt = 0; kt < 512; kt += 16) {
        {   // A tile 64x16
            const int r = tid >> 2;
            const int c = (tid & 3) << 2;
            const float4 a4 = *(const float4*)(A + (long long)(m0 + r) * 512 + kt + c);
            As[r][c+0] = a4.x; As[r][c+1] = a4.y; As[r][c+2] = a4.z; As[r][c+3] = a4.w;
        }
        {   // B tile 16x64
            const int r = tid >> 4;
            const int c = (tid & 15) << 2;
            *(float4*)(&Bs[r][c]) = *(const float4*)(W + (long long)(kt + r) * 512 + n0 + c);
        }
        __syncthreads();
#pragma unroll
        for (int k = 0; k < 16; ++k) {
            float a[4];
#pragma unroll
            for (int i = 0; i < 4; ++i) a[i] = As[ty*4+i][k];
            const float4 b4 = *(const float4*)(&Bs[k][tx*4]);
            const float b[4] = {b4.x, b4.y, b4.z, b4.w};
#pragma unroll
            for (int i = 0; i < 4; ++i)
#pragma unroll
                for (int j = 0; j < 4; ++j) acc[i][j] += a[i] * b[j];
        }
        __syncthreads();
    }

#pragma unroll
    for (int i = 0; i < 4; ++i) {
        const int m = m0 + ty*4 + i;
        float4 r4;
        r4.x = acc[i][0] + bias[n0 + tx*4 + 0];
        r4.y = acc[i][1] + bias[n0 + tx*4 + 1];
        r4.z = acc[i][2] + bias[n0 + tx*4 + 2];
        r4.w = acc[i][3] + bias[n0 + tx*4 + 3];
        if (MODE == 0) {
            const int bb = m >> 11, n = m & 2047;
            const int h  = n0 >> 6;                   // TILE_N == 64 == D_K
            *(float4*)(out + (((long long)(bb*H_ + h))*NQ_ + n)*DK_ + tx*4) = r4;
        } else {
            *(float4*)(out + (long long)m*512 + n0 + tx*4) = r4;
        }
    }
}

// ---------------------------------------------------------------------------
// Fused attention: per block one (b,h) and 64 q-rows; stream K/V in 64-row
// tiles with online softmax. s = (q.k)*0.125*w ; mask==true -> -1e30.
// ---------------------------------------------------------------------------
__global__ __launch_bounds__(256) void attn64(const float* __restrict__ Q,
                                              const float* __restrict__ K,
                                              const float* __restrict__ V,
                                              const float* __restrict__ Wt,
                                              const unsigned char* __restrict__ Mk,
                                              float* __restrict__ O)
{
    __shared__ float Qt[64][64];   // [d][r]  (transposed)
    __shared__ float Kt[64][64];   // [d][c]  (transposed)
    __shared__ float Vs[64][64];   // [k][c]
    __shared__ float Ps[64][68];   // [r][k]  pad 68: broadcast reads conflict-free
    __shared__ int   s_flag;

    const int tid = threadIdx.x;
    const int tx = tid & 15, ty = tid >> 4;
    const int q0 = blockIdx.x * 64;
    const int bh = blockIdx.y;                       // b*H + h
    const long long qkvBase = (long long)bh * NK_ * DK_;
    const long long wBase   = (long long)bh * NQ_ * NK_;

    // --- detect mask element size: bytes at (idx%4==1) are 0 for int32/float32,
    //     nonzero w.p. 0.1/elem for 1-byte bool. Scan 4096 bytes. ---
    if (tid == 0) s_flag = 0;
    __syncthreads();
    {
        bool any = false;
#pragma unroll
        for (int i = 1; i < 16; i += 4)
            if (Mk[tid*16 + i]) any = true;
        if (any) s_flag = 1;
    }

    // --- load Q tile transposed ---
    {
        const int r  = tid >> 2;
        const int cb = (tid & 3) << 4;
#pragma unroll
        for (int j = 0; j < 4; ++j) {
            const float4 v4 = *(const float4*)(Q + qkvBase + (long long)(q0 + r)*DK_ + cb + 4*j);
            Qt[cb+4*j+0][r] = v4.x;
            Qt[cb+4*j+1][r] = v4.y;
            Qt[cb+4*j+2][r] = v4.z;
            Qt[cb+4*j+3][r] = v4.w;
        }
    }
    __syncthreads();
    const bool maskByte = (s_flag != 0);

    float o[4][4] = {};
    float m_r[4], l_r[4];
#pragma unroll
    for (int i = 0; i < 4; ++i) { m_r[i] = -1e30f; l_r[i] = 0.f; }

    for (int kt0 = 0; kt0 < NK_; kt0 += 64) {
        // --- load K (transposed) and V tiles ---
        {
            const int r  = tid >> 2;
            const int cb = (tid & 3) << 4;
#pragma unroll
            for (int j = 0; j < 4; ++j) {
                const long long g = qkvBase + (long long)(kt0 + r)*DK_ + cb + 4*j;
                const float4 k4 = *(const float4*)(K + g);
                Kt[cb+4*j+0][r] = k4.x;
                Kt[cb+4*j+1][r] = k4.y;
                Kt[cb+4*j+2][r] = k4.z;
                Kt[cb+4*j+3][r] = k4.w;
                *(float4*)(&Vs[r][cb+4*j]) = *(const float4*)(V + g);
            }
        }
        __syncthreads();

        // --- S = Q K^T : rows 4ty+i, cols 4tx+j ---
        float s[4][4] = {};
#pragma unroll
        for (int d = 0; d < 64; ++d) {
            const float4 a4 = *(const float4*)(&Qt[d][ty*4]);
            const float4 b4 = *(const float4*)(&Kt[d][tx*4]);
            const float a[4] = {a4.x,a4.y,a4.z,a4.w};
            const float b[4] = {b4.x,b4.y,b4.z,b4.w};
#pragma unroll
            for (int i = 0; i < 4; ++i)
#pragma unroll
                for (int j = 0; j < 4; ++j) s[i][j] += a[i]*b[j];
        }

        // --- scale * weights, apply mask ---
#pragma unroll
        for (int i = 0; i < 4; ++i) {
            const long long rowOff = wBase + (long long)(q0 + 4*ty + i)*NK_ + kt0 + 4*tx;
            const float4 w4 = *(const float4*)(Wt + rowOff);
            unsigned int mb[4];
            if (maskByte) {
                const unsigned int mu = *(const unsigned int*)(Mk + rowOff);
                mb[0] =  mu        & 0xffu;
                mb[1] = (mu >> 8)  & 0xffu;
                mb[2] = (mu >> 16) & 0xffu;
                mb[3] = (mu >> 24) & 0xffu;
            } else {
                const uint4 mi = *(const uint4*)((const unsigned int*)Mk + rowOff);
                mb[0] = mi.x; mb[1] = mi.y; mb[2] = mi.z; mb[3] = mi.w;
            }
            const float w[4] = {w4.x, w4.y, w4.z, w4.w};
#pragma unroll
            for (int j = 0; j < 4; ++j)
                s[i][j] = mb[j] ? -1e30f : s[i][j] * 0.125f * w[j];
        }

        // --- online softmax (row reduce across the 16-lane tx group) ---
#pragma unroll
        for (int i = 0; i < 4; ++i) {
            float tm = fmaxf(fmaxf(s[i][0], s[i][1]), fmaxf(s[i][2], s[i][3]));
#pragma unroll
            for (int off = 1; off < 16; off <<= 1)
                tm = fmaxf(tm, __shfl_xor(tm, off, 64));
            const float mn  = fmaxf(m_r[i], tm);
            const float fsc = __expf(m_r[i] - mn);
            float p[4], rs = 0.f;
#pragma unroll
            for (int j = 0; j < 4; ++j) { p[j] = __expf(s[i][j] - mn); rs += p[j]; }
#pragma unroll
            for (int off = 1; off < 16; off <<= 1)
                rs += __shfl_xor(rs, off, 64);
            l_r[i] = l_r[i]*fsc + rs;
            m_r[i] = mn;
#pragma unroll
            for (int j = 0; j < 4; ++j) o[i][j] *= fsc;
            *(float4*)(&Ps[4*ty+i][4*tx]) = make_float4(p[0], p[1], p[2], p[3]);
        }
        __syncthreads();

        // --- O += P V ---
#pragma unroll
        for (int kk = 0; kk < 64; ++kk) {
            const float4 v4 = *(const float4*)(&Vs[kk][4*tx]);
            const float vv[4] = {v4.x, v4.y, v4.z, v4.w};
            float pr[4];
#pragma unroll
            for (int i = 0; i < 4; ++i) pr[i] = Ps[4*ty+i][kk];
#pragma unroll
            for (int i = 0; i < 4; ++i)
#pragma unroll
                for (int j = 0; j < 4; ++j) o[i][j] += pr[i]*vv[j];
        }
        __syncthreads();
    }

    // --- epilogue: normalize, write (b, q, h*64+d) ---
    const int bb = bh >> 3, h = bh & 7;
#pragma unroll
    for (int i = 0; i < 4; ++i) {
        const float inv = 1.0f / l_r[i];
        const float4 r4 = make_float4(o[i][0]*inv, o[i][1]*inv, o[i][2]*inv, o[i][3]*inv);
        *(float4*)(O + ((long long)(bb*NQ_ + q0 + 4*ty + i))*512 + h*64 + 4*tx) = r4;
    }
}

// ---------------------------------------------------------------------------
extern "C" void kernel_launch(void* const* d_in, const int* in_sizes, int n_in,
                              void* d_out, int out_size, void* d_ws, size_t ws_size,
                              hipStream_t stream) {
    (void)in_sizes; (void)n_in; (void)out_size; (void)ws_size;

    const float* q    = (const float*)d_in[0];
    const float* k    = (const float*)d_in[1];
    const float* v    = (const float*)d_in[2];
    const float* attw = (const float*)d_in[3];
    const unsigned char* mask = (const unsigned char*)d_in[4];
    const float* Wq = (const float*)d_in[5];
    const float* bq = (const float*)d_in[6];
    const float* Wk = (const float*)d_in[7];
    const float* bk = (const float*)d_in[8];
    const float* Wv = (const float*)d_in[9];
    const float* bv = (const float*)d_in[10];
    const float* Wo = (const float*)d_in[11];
    const float* bo = (const float*)d_in[12];
    float* out = (float*)d_out;

    // workspace layout (floats): q,k,v in (B,H,N,64) + attention output (B*NQ,512)
    float* ws   = (float*)d_ws;
    float* q_ws = ws;
    float* k_ws = ws + (long long)B_*H_*NQ_*DK_;      // +4 Mi floats
    float* v_ws = ws + 2LL*B_*H_*NQ_*DK_;
    float* o_ws = ws + 3LL*B_*H_*NQ_*DK_;             // (8192 x 512)

    const dim3 blk(256);
    const dim3 gproj(128, 8);
    gemm512<0><<<gproj, blk, 0, stream>>>(q, Wq, bq, q_ws);
    gemm512<0><<<gproj, blk, 0, stream>>>(k, Wk, bk, k_ws);
    gemm512<0><<<gproj, blk, 0, stream>>>(v, Wv, bv, v_ws);

    attn64<<<dim3(NQ_/64, B_*H_), blk, 0, stream>>>(q_ws, k_ws, v_ws, attw, mask, o_ws);

    gemm512<1><<<gproj, blk, 0, stream>>>(o_ws, Wo, bo, out);
}

// Round 2
// 641.668 us; speedup vs baseline: 7.0565x; 7.0565x over previous
//
#include <hip/hip_runtime.h>
#include <hip/hip_bf16.h>
#include <math.h>

#define B_   4
#define H_   8
#define NQ_  2048
#define NK_  2048
#define DM_  512
#define DK_  64

typedef short  bf16x8 __attribute__((ext_vector_type(8)));
typedef float  f32x4  __attribute__((ext_vector_type(4)));

static __device__ __forceinline__ f32x4 MFMA16(bf16x8 a, bf16x8 b, f32x4 c) {
    return __builtin_amdgcn_mfma_f32_16x16x32_bf16(a, b, c, 0, 0, 0);
}

static __device__ __forceinline__ unsigned short f2bf(float f) {
    __hip_bfloat16 h = __float2bfloat16(f);
    unsigned short u;
    __builtin_memcpy(&u, &h, 2);
    return u;
}

// ---------------------------------------------------------------------------
// GEMM: X (M x 512) @ W (512 x 512) + bias.
// MODE 0: bf16 out in (B, H, N, 64) layout (head = n-tile since TILE_N==64)
// MODE 1: fp32 out, plain row-major M x 512
// ---------------------------------------------------------------------------
template<int MODE>
__global__ __launch_bounds__(256) void gemm512(const float* __restrict__ A,
                                               const float* __restrict__ W,
                                               const float* __restrict__ bias,
                                               void* __restrict__ outv)
{
    __shared__ float As[64][17];
    __shared__ float Bs[16][64];

    const int tid = threadIdx.x;
    const int tx = tid & 15, ty = tid >> 4;
    const int m0 = blockIdx.x * 64, n0 = blockIdx.y * 64;

    float acc[4][4] = {};

    for (int kt = 0; kt < 512; kt += 16) {
        {
            const int r = tid >> 2;
            const int c = (tid & 3) << 2;
            const float4 a4 = *(const float4*)(A + (long long)(m0 + r) * 512 + kt + c);
            As[r][c+0] = a4.x; As[r][c+1] = a4.y; As[r][c+2] = a4.z; As[r][c+3] = a4.w;
        }
        {
            const int r = tid >> 4;
            const int c = (tid & 15) << 2;
            *(float4*)(&Bs[r][c]) = *(const float4*)(W + (long long)(kt + r) * 512 + n0 + c);
        }
        __syncthreads();
#pragma unroll
        for (int k = 0; k < 16; ++k) {
            float a[4];
#pragma unroll
            for (int i = 0; i < 4; ++i) a[i] = As[ty*4+i][k];
            const float4 b4 = *(const float4*)(&Bs[k][tx*4]);
            const float b[4] = {b4.x, b4.y, b4.z, b4.w};
#pragma unroll
            for (int i = 0; i < 4; ++i)
#pragma unroll
                for (int j = 0; j < 4; ++j) acc[i][j] += a[i] * b[j];
        }
        __syncthreads();
    }

#pragma unroll
    for (int i = 0; i < 4; ++i) {
        const int m = m0 + ty*4 + i;
        float r[4];
#pragma unroll
        for (int j = 0; j < 4; ++j) r[j] = acc[i][j] + bias[n0 + tx*4 + j];
        if (MODE == 0) {
            const int bb = m >> 11, n = m & 2047;
            const int h  = n0 >> 6;
            ushort4 u;
            u.x = f2bf(r[0]); u.y = f2bf(r[1]); u.z = f2bf(r[2]); u.w = f2bf(r[3]);
            *(ushort4*)((unsigned short*)outv +
                        (((long long)(bb*H_ + h))*NQ_ + n)*DK_ + tx*4) = u;
        } else {
            *(float4*)((float*)outv + (long long)m*512 + n0 + tx*4) =
                make_float4(r[0], r[1], r[2], r[3]);
        }
    }
}

// ---------------------------------------------------------------------------
// V (bh, key, dv) bf16 -> VT (bh, dv, key) bf16, 64x64 LDS tiles
// ---------------------------------------------------------------------------
__global__ __launch_bounds__(256) void transpose_v(const unsigned short* __restrict__ V,
                                                   unsigned short* __restrict__ VT)
{
    __shared__ unsigned short tile[64][68];
    const int tid = threadIdx.x;
    const int k0  = blockIdx.x * 64;
    const size_t base  = (size_t)blockIdx.y * NK_ * DK_;

#pragma unroll
    for (int i = 0; i < 4; ++i) {
        const int idx = tid + 256*i;
        const int key = idx >> 4, dvc = (idx & 15) << 2;
        const ushort4 u = *(const ushort4*)(V + base + (size_t)(k0 + key)*DK_ + dvc);
        tile[key][dvc+0] = u.x; tile[key][dvc+1] = u.y;
        tile[key][dvc+2] = u.z; tile[key][dvc+3] = u.w;
    }
    __syncthreads();
#pragma unroll
    for (int i = 0; i < 4; ++i) {
        const int idx = tid + 256*i;
        const int dv = idx >> 4, key4 = (idx & 15) << 2;
        ushort4 u;
        u.x = tile[key4+0][dv]; u.y = tile[key4+1][dv];
        u.z = tile[key4+2][dv]; u.w = tile[key4+3][dv];
        *(ushort4*)(VT + base + (size_t)dv*NK_ + k0 + key4) = u;
    }
}

// ---------------------------------------------------------------------------
// MFMA flash attention. 4 waves/block, 16 q-rows/wave, K-tiles of 64.
// S^T = mfma(K, Q) -> lane holds qrow = lane&15, keys 16t+4g+reg.
// Softmax per lane + shfl_xor(16,32). P -> swizzled wave-private LDS ->
// PV A-fragment. O = mfma(P, V^T-frag). No __syncthreads in the loop.
// ---------------------------------------------------------------------------
__global__ __launch_bounds__(256, 2) void attn_mfma(
    const unsigned short* __restrict__ Qb,
    const unsigned short* __restrict__ Kb,
    const unsigned short* __restrict__ Vt,
    const float* __restrict__ Wt,
    const unsigned char* __restrict__ Mk,
    float* __restrict__ O)
{
    __shared__ short Pl[4][1024];      // 2KB per wave, swizzled
    __shared__ int   s_flag;

    const int tid  = threadIdx.x;
    const int wid  = tid >> 6;
    const int lane = tid & 63;
    const int g    = lane >> 4;
    const int r    = lane & 15;
    const int q0   = blockIdx.x * 64 + wid * 16;
    const int bh   = blockIdx.y;

    // mask elem-size detection (bytes at idx%4==1 are 0 for 4-byte dtypes)
    if (tid == 0) s_flag = 0;
    __syncthreads();
    {
        bool any = false;
#pragma unroll
        for (int i = 1; i < 16; i += 4)
            if (Mk[tid*16 + i]) any = true;
        if (any) s_flag = 1;
    }

    const size_t kvBase = (size_t)bh * NK_ * DK_;

    // Q fragments (2 k-steps)
    const unsigned short* qp = Qb + kvBase + (size_t)(q0 + r) * DK_ + 8*g;
    bf16x8 qf0 = *(const bf16x8*)(qp);
    bf16x8 qf1 = *(const bf16x8*)(qp + 32);

    __syncthreads();
    const bool mByte = (s_flag != 0);

    const size_t wBase = ((size_t)bh * NQ_ + q0 + r) * NK_;
    const float*         wrow  = Wt + wBase;
    const unsigned char* mrow  = Mk + wBase;
    const unsigned int*  mrow4 = (const unsigned int*)Mk + wBase;

    const f32x4 zero4 = {0.f, 0.f, 0.f, 0.f};
    f32x4 oa[4] = {zero4, zero4, zero4, zero4};
    float m_run = -1e30f, l_run = 0.f;

    char* pbase = (char*)&Pl[wid][0];
    const int roff = r * 128;
    const int sw   = (r & 7) << 4;

    for (int kt = 0; kt < NK_; kt += 64) {
        // ---- S^T = K . Q^T over 4 key-tiles ----
        f32x4 sa[4] = {zero4, zero4, zero4, zero4};
#pragma unroll
        for (int t = 0; t < 4; ++t) {
            const unsigned short* kp = Kb + kvBase + (size_t)(kt + 16*t + r)*DK_ + 8*g;
            const bf16x8 kf0 = *(const bf16x8*)(kp);
            const bf16x8 kf1 = *(const bf16x8*)(kp + 32);
            sa[t] = MFMA16(kf0, qf0, sa[t]);
            sa[t] = MFMA16(kf1, qf1, sa[t]);
        }

        // ---- logits = mask ? -1e30 : s * 0.125 * w ----
        float lg[16];
#pragma unroll
        for (int t = 0; t < 4; ++t) {
            const float4 w4 = *(const float4*)(wrow + kt + 16*t + 4*g);
            const float wv[4] = {w4.x, w4.y, w4.z, w4.w};
            unsigned int mb[4];
            if (mByte) {
                const unsigned int mu = *(const unsigned int*)(mrow + kt + 16*t + 4*g);
                mb[0] =  mu        & 0xffu;
                mb[1] = (mu >> 8)  & 0xffu;
                mb[2] = (mu >> 16) & 0xffu;
                mb[3] = (mu >> 24) & 0xffu;
            } else {
                const uint4 mi = *(const uint4*)(mrow4 + kt + 16*t + 4*g);
                mb[0] = mi.x; mb[1] = mi.y; mb[2] = mi.z; mb[3] = mi.w;
            }
#pragma unroll
            for (int j = 0; j < 4; ++j)
                lg[4*t+j] = mb[j] ? -1e30f : sa[t][j] * 0.125f * wv[j];
        }

        // ---- online softmax (qrow = r; reduce across g via shfl 16,32) ----
        float mx = lg[0];
#pragma unroll
        for (int i = 1; i < 16; ++i) mx = fmaxf(mx, lg[i]);
        mx = fmaxf(mx, __shfl_xor(mx, 16, 64));
        mx = fmaxf(mx, __shfl_xor(mx, 32, 64));
        const float mnew = fmaxf(m_run, mx);
        const float fsc  = __expf(m_run - mnew);
        m_run = mnew;

        float p[16], rs = 0.f;
#pragma unroll
        for (int i = 0; i < 16; ++i) { p[i] = __expf(lg[i] - mnew); rs += p[i]; }
        rs += __shfl_xor(rs, 16, 64);
        rs += __shfl_xor(rs, 32, 64);
        l_run = l_run * fsc + rs;

        // ---- pack P -> wave-private swizzled LDS ----
#pragma unroll
        for (int t = 0; t < 4; ++t) {
            const unsigned int w0 = (unsigned int)f2bf(p[4*t+0]) |
                                    ((unsigned int)f2bf(p[4*t+1]) << 16);
            const unsigned int w1 = (unsigned int)f2bf(p[4*t+2]) |
                                    ((unsigned int)f2bf(p[4*t+3]) << 16);
            *(int2*)(pbase + roff + ((32*t + 8*g) ^ sw)) = make_int2((int)w0, (int)w1);
        }
        asm volatile("s_waitcnt lgkmcnt(0)" ::: "memory");
        __builtin_amdgcn_sched_barrier(0);
        const bf16x8 pa0 = *(const bf16x8*)(pbase + roff + ((      16*g) ^ sw));
        const bf16x8 pa1 = *(const bf16x8*)(pbase + roff + ((64 + 16*g) ^ sw));

        // ---- rescale O by exp(m_old - m_new) for this lane's 4 q-rows ----
        float fr[4];
#pragma unroll
        for (int j = 0; j < 4; ++j) fr[j] = __shfl(fsc, 4*g + j, 64);
#pragma unroll
        for (int nt = 0; nt < 4; ++nt)
#pragma unroll
            for (int j = 0; j < 4; ++j) oa[nt][j] *= fr[j];

        // ---- O += P . V  (V^T fragments: dv = 16nt + r, key contiguous) ----
#pragma unroll
        for (int s = 0; s < 2; ++s) {
            const bf16x8 pa = s ? pa1 : pa0;
#pragma unroll
            for (int nt = 0; nt < 4; ++nt) {
                const bf16x8 vf = *(const bf16x8*)(Vt + kvBase +
                                     (size_t)(16*nt + r)*NK_ + kt + 32*s + 8*g);
                oa[nt] = MFMA16(pa, vf, oa[nt]);
            }
        }
    }

    // ---- epilogue: normalize + write (b, q, h*64+dv) fp32 ----
    const float inv = 1.0f / l_run;
    float ir[4];
#pragma unroll
    for (int j = 0; j < 4; ++j) ir[j] = __shfl(inv, 4*g + j, 64);
    const int bb = bh >> 3, h = bh & 7;
#pragma unroll
    for (int nt = 0; nt < 4; ++nt)
#pragma unroll
        for (int j = 0; j < 4; ++j)
            O[((size_t)(bb*NQ_ + q0 + 4*g + j))*DM_ + h*64 + 16*nt + r] = oa[nt][j] * ir[j];
}

// ---------------------------------------------------------------------------
extern "C" void kernel_launch(void* const* d_in, const int* in_sizes, int n_in,
                              void* d_out, int out_size, void* d_ws, size_t ws_size,
                              hipStream_t stream) {
    (void)in_sizes; (void)n_in; (void)out_size; (void)ws_size;

    const float* q    = (const float*)d_in[0];
    const float* k    = (const float*)d_in[1];
    const float* v    = (const float*)d_in[2];
    const float* attw = (const float*)d_in[3];
    const unsigned char* mask = (const unsigned char*)d_in[4];
    const float* Wq = (const float*)d_in[5];
    const float* bq = (const float*)d_in[6];
    const float* Wk = (const float*)d_in[7];
    const float* bk = (const float*)d_in[8];
    const float* Wv = (const float*)d_in[9];
    const float* bv = (const float*)d_in[10];
    const float* Wo = (const float*)d_in[11];
    const float* bo = (const float*)d_in[12];
    float* out = (float*)d_out;

    // ws: q_bf, k_bf, v_bf, vT (bf16, 4Mi elems each) then o_ws fp32 (4Mi)
    const long long NE = (long long)B_*H_*NQ_*DK_;   // 4Mi
    unsigned short* q_bf = (unsigned short*)d_ws;
    unsigned short* k_bf = q_bf + NE;
    unsigned short* v_bf = q_bf + 2*NE;
    unsigned short* vT   = q_bf + 3*NE;
    float*          o_ws = (float*)(q_bf + 4*NE);

    const dim3 blk(256);
    const dim3 gproj(128, 8);
    gemm512<0><<<gproj, blk, 0, stream>>>(q, Wq, bq, q_bf);
    gemm512<0><<<gproj, blk, 0, stream>>>(k, Wk, bk, k_bf);
    gemm512<0><<<gproj, blk, 0, stream>>>(v, Wv, bv, v_bf);

    transpose_v<<<dim3(NK_/64, B_*H_), blk, 0, stream>>>(v_bf, vT);

    attn_mfma<<<dim3(NQ_/64, B_*H_), blk, 0, stream>>>(q_bf, k_bf, vT, attw, mask, o_ws);

    gemm512<1><<<gproj, blk, 0, stream>>>(o_ws, Wo, bo, out);
}

// Round 3
// 603.321 us; speedup vs baseline: 7.5050x; 1.0636x over previous
//
#include <hip/hip_runtime.h>
#include <hip/hip_bf16.h>
#include <math.h>

#define B_   4
#define H_   8
#define NQ_  2048
#define NK_  2048
#define DM_  512
#define DK_  64
#define WL_  262144   // 512*512

typedef short  bf16x8 __attribute__((ext_vector_type(8)));
typedef float  f32x4  __attribute__((ext_vector_type(4)));

static __device__ __forceinline__ f32x4 MFMA16(bf16x8 a, bf16x8 b, f32x4 c) {
    return __builtin_amdgcn_mfma_f32_16x16x32_bf16(a, b, c, 0, 0, 0);
}
static __device__ __forceinline__ unsigned short f2bf(float f) {
    __hip_bfloat16 h = __float2bfloat16(f);
    unsigned short u; __builtin_memcpy(&u, &h, 2); return u;
}
static __device__ __forceinline__ float bf2f(unsigned short u) {
    unsigned int x = ((unsigned int)u) << 16;
    float f; __builtin_memcpy(&f, &x, 4); return f;
}

// ---------------------------------------------------------------------------
// W (512x512 fp32, [k][n]) -> WT_hi/WT_lo (bf16, [n][k]) for all 4 weights
// ---------------------------------------------------------------------------
__global__ __launch_bounds__(256) void wprep(const float* __restrict__ Wq,
                                             const float* __restrict__ Wk,
                                             const float* __restrict__ Wv,
                                             const float* __restrict__ Wo,
                                             unsigned short* __restrict__ out)
{
    __shared__ float tile[64][65];
    const int tid = threadIdx.x;
    const int k0 = blockIdx.x * 64, n0 = blockIdx.y * 64, w = blockIdx.z;
    const float* W = (w == 0) ? Wq : (w == 1) ? Wk : (w == 2) ? Wv : Wo;
    unsigned short* WTh = out + (size_t)w * 2 * WL_;
    unsigned short* WTl = WTh + WL_;

#pragma unroll
    for (int rd = 0; rd < 4; ++rd) {
        const int k = (tid >> 4) + 16*rd, c4 = (tid & 15) * 4;
        const float4 v4 = *(const float4*)(W + (size_t)(k0 + k)*DM_ + n0 + c4);
        tile[k][c4+0] = v4.x; tile[k][c4+1] = v4.y;
        tile[k][c4+2] = v4.z; tile[k][c4+3] = v4.w;
    }
    __syncthreads();
#pragma unroll
    for (int rd = 0; rd < 4; ++rd) {
        const int n = (tid >> 4) + 16*rd, kk = (tid & 15) * 4;
        unsigned short hh[4], ll[4];
#pragma unroll
        for (int j = 0; j < 4; ++j) {
            const float f = tile[kk + j][n];
            hh[j] = f2bf(f);
            ll[j] = f2bf(f - bf2f(hh[j]));
        }
        *(ushort4*)(WTh + (size_t)(n0 + n)*DM_ + k0 + kk) = make_ushort4(hh[0],hh[1],hh[2],hh[3]);
        *(ushort4*)(WTl + (size_t)(n0 + n)*DM_ + k0 + kk) = make_ushort4(ll[0],ll[1],ll[2],ll[3]);
    }
}

// ---------------------------------------------------------------------------
// Split-bf16 MFMA GEMM: C = A(fp32) @ W + bias, via Ah*Wh + Ah*Wl + Al*Wh.
// MODE 0: bf16 out, (B,H,N,64) layout (q/k projections)
// MODE 1: bf16 out, transposed (B,H,64,NK) layout (v projection -> V^T)
// MODE 2: fp32 out, row-major MxDM + bias (final)
// 64x64 tile, BK=64, 4 waves; XOR-swizzled LDS (byte ^= (row&7)<<4).
// ---------------------------------------------------------------------------
template<int MODE>
__global__ __launch_bounds__(256) void gemm_split(
    const float* __restrict__ A,
    const unsigned short* __restrict__ WTh,
    const unsigned short* __restrict__ WTl,
    const float* __restrict__ bias,
    void* __restrict__ outv)
{
    __shared__ unsigned short Ah[64][64], Al[64][64], Bh[64][64], Bl[64][64];

    const int tid = threadIdx.x;
    const int w = tid >> 6, lane = tid & 63, g = lane >> 4, r = lane & 15;
    const int m0 = blockIdx.x * 64, n0 = blockIdx.y * 64;

    char* pAh = (char*)&Ah[0][0];
    char* pAl = (char*)&Al[0][0];
    char* pBh = (char*)&Bh[0][0];
    char* pBl = (char*)&Bl[0][0];

    const f32x4 z4 = {0.f, 0.f, 0.f, 0.f};
    f32x4 acc[4] = {z4, z4, z4, z4};

    for (int kt = 0; kt < DM_; kt += 64) {
        // ---- stage A tile (fp32 -> hi/lo bf16), swizzled ----
#pragma unroll
        for (int rd = 0; rd < 4; ++rd) {
            const int row = (tid >> 4) + 16*rd;
            const int c4  = (tid & 15) * 4;
            const float4 a4 = *(const float4*)(A + (size_t)(m0 + row)*DM_ + kt + c4);
            const float av[4] = {a4.x, a4.y, a4.z, a4.w};
            unsigned short hh[4], ll[4];
#pragma unroll
            for (int j = 0; j < 4; ++j) {
                hh[j] = f2bf(av[j]);
                ll[j] = f2bf(av[j] - bf2f(hh[j]));
            }
            const int bo = (c4 * 2) ^ ((row & 7) << 4);
            *(ushort4*)(pAh + row*128 + bo) = make_ushort4(hh[0],hh[1],hh[2],hh[3]);
            *(ushort4*)(pAl + row*128 + bo) = make_ushort4(ll[0],ll[1],ll[2],ll[3]);
        }
        // ---- stage W^T hi/lo tiles (bf16 direct), swizzled ----
#pragma unroll
        for (int rd = 0; rd < 2; ++rd) {
            const int idx = tid + 256*rd;
            const int row = idx >> 3;
            const int cb  = (idx & 7) * 16;          // byte offset (8 bf16)
            const int bo  = cb ^ ((row & 7) << 4);
            const size_t goff = (size_t)(n0 + row)*DM_ + kt + (cb >> 1);
            *(bf16x8*)(pBh + row*128 + bo) = *(const bf16x8*)(WTh + goff);
            *(bf16x8*)(pBl + row*128 + bo) = *(const bf16x8*)(WTl + goff);
        }
        __syncthreads();

        const int swr = (r & 7) << 4;
#pragma unroll
        for (int ks = 0; ks < 2; ++ks) {
            const int xo = (64*ks + 16*g) ^ swr;
            const bf16x8 xh = *(const bf16x8*)(pAh + (16*w + r)*128 + xo);
            const bf16x8 xl = *(const bf16x8*)(pAl + (16*w + r)*128 + xo);
#pragma unroll
            for (int nt = 0; nt < 4; ++nt) {
                const bf16x8 bh = *(const bf16x8*)(pBh + (16*nt + r)*128 + xo);
                const bf16x8 bl = *(const bf16x8*)(pBl + (16*nt + r)*128 + xo);
                if (MODE == 1) {      // A-operand = X rows (keys), B-operand = W^T
                    acc[nt] = MFMA16(xh, bh, acc[nt]);
                    acc[nt] = MFMA16(xh, bl, acc[nt]);
                    acc[nt] = MFMA16(xl, bh, acc[nt]);
                } else {              // A-operand = W^T rows (n), B-operand = X
                    acc[nt] = MFMA16(bh, xh, acc[nt]);
                    acc[nt] = MFMA16(bh, xl, acc[nt]);
                    acc[nt] = MFMA16(bl, xh, acc[nt]);
                }
            }
        }
        __syncthreads();
    }

    // ---- epilogue ----
    if (MODE == 0) {
        const int m = m0 + 16*w + r;
        const int b = m >> 11, q = m & 2047, h = blockIdx.y;
        unsigned short* dst = (unsigned short*)outv + (((size_t)(b*H_ + h))*NQ_ + q)*DK_;
#pragma unroll
        for (int nt = 0; nt < 4; ++nt) {
            unsigned short u[4];
#pragma unroll
            for (int j = 0; j < 4; ++j)
                u[j] = f2bf(acc[nt][j] + bias[n0 + 16*nt + 4*g + j]);
            *(ushort4*)(dst + 16*nt + 4*g) = make_ushort4(u[0],u[1],u[2],u[3]);
        }
    } else if (MODE == 1) {
        const int b = m0 >> 11, h = blockIdx.y;
        const int key = (m0 & 2047) + 16*w + 4*g;
#pragma unroll
        for (int nt = 0; nt < 4; ++nt) {
            const int dv = 16*nt + r;
            const float bv = bias[n0 + dv];
            unsigned short u[4];
#pragma unroll
            for (int j = 0; j < 4; ++j) u[j] = f2bf(acc[nt][j] + bv);
            *(ushort4*)((unsigned short*)outv +
                        (((size_t)(b*H_ + h))*DK_ + dv)*NK_ + key) = make_ushort4(u[0],u[1],u[2],u[3]);
        }
    } else {
        const int m = m0 + 16*w + r;
        float* dst = (float*)outv + (size_t)m*DM_ + n0;
#pragma unroll
        for (int nt = 0; nt < 4; ++nt) {
            float4 o4;
            o4.x = acc[nt][0] + bias[n0 + 16*nt + 4*g + 0];
            o4.y = acc[nt][1] + bias[n0 + 16*nt + 4*g + 1];
            o4.z = acc[nt][2] + bias[n0 + 16*nt + 4*g + 2];
            o4.w = acc[nt][3] + bias[n0 + 16*nt + 4*g + 3];
            *(float4*)(dst + 16*nt + 4*g) = o4;
        }
    }
}

// ---------------------------------------------------------------------------
// MFMA flash attention, 2-way key-split, W/mask prefetched one tile ahead.
// 4 waves/block: qg = wid>>1 (16 q-rows each), ph = wid&1 (key phase).
// Phase ph handles kt = 128*i + 64*ph; results flash-merged at the end.
// ---------------------------------------------------------------------------
__global__ __launch_bounds__(256, 4) void attn_mfma(
    const unsigned short* __restrict__ Qb,
    const unsigned short* __restrict__ Kb,
    const unsigned short* __restrict__ Vt,
    const float* __restrict__ Wt,
    const unsigned char* __restrict__ Mk,
    float* __restrict__ O)
{
    __shared__ short Pl[4][1024];
    __shared__ float Msh[2][16], Lsh[2][16];
    __shared__ float Osh[2][64][16];
    __shared__ int   s_flag;

    const int tid  = threadIdx.x;
    const int wid  = tid >> 6, lane = tid & 63;
    const int g    = lane >> 4, r = lane & 15;
    const int qg   = wid >> 1, ph = wid & 1;
    const int q0   = blockIdx.x * 32 + qg * 16;
    const int bh   = blockIdx.y;

    if (tid == 0) s_flag = 0;
    __syncthreads();
    {
        bool any = false;
#pragma unroll
        for (int i = 1; i < 16; i += 4)
            if (Mk[tid*16 + i]) any = true;
        if (any) s_flag = 1;
    }

    const size_t kvBase = (size_t)bh * NK_ * DK_;
    const unsigned short* qp = Qb + kvBase + (size_t)(q0 + r)*DK_ + 8*g;
    const bf16x8 qf0 = *(const bf16x8*)qp;
    const bf16x8 qf1 = *(const bf16x8*)(qp + 32);
    __syncthreads();
    const bool mByte = (s_flag != 0);

    const size_t wBase = ((size_t)bh * NQ_ + q0 + r) * NK_;
    const float*         wrow  = Wt + wBase;
    const unsigned char* mrow  = Mk + wBase;
    const unsigned int*  mrow4 = (const unsigned int*)Mk + wBase;

    const f32x4 zero4 = {0.f, 0.f, 0.f, 0.f};
    f32x4 oa[4] = {zero4, zero4, zero4, zero4};
    float m_run = -1e30f, l_run = 0.f;

    char* pbase = (char*)&Pl[wid][0];
    const int roff = r * 128;
    const int sw   = (r & 7) << 4;

    // prefetch W/mask for the first tile
    int kt = 64 * ph;
    float4 wc[4]; unsigned int mc[4];
#pragma unroll
    for (int t = 0; t < 4; ++t) {
        wc[t] = *(const float4*)(wrow + kt + 16*t + 4*g);
        mc[t] = mByte ? *(const unsigned int*)(mrow + kt + 16*t + 4*g) : 0u;
    }

#pragma unroll 1
    for (int i = 0; i < 16; ++i) {
        // ---- S^T = K . Q^T ----
        f32x4 sa[4] = {zero4, zero4, zero4, zero4};
#pragma unroll
        for (int t = 0; t < 4; ++t) {
            const unsigned short* kp = Kb + kvBase + (size_t)(kt + 16*t + r)*DK_ + 8*g;
            sa[t] = MFMA16(*(const bf16x8*)kp,        qf0, sa[t]);
            sa[t] = MFMA16(*(const bf16x8*)(kp + 32), qf1, sa[t]);
        }

        // ---- issue next-tile W/mask (HBM) + current V^T s=0 (L2) ----
        const int ktn = (kt + 128 < NK_) ? kt + 128 : kt;
        float4 wn[4]; unsigned int mn[4];
#pragma unroll
        for (int t = 0; t < 4; ++t) {
            wn[t] = *(const float4*)(wrow + ktn + 16*t + 4*g);
            mn[t] = mByte ? *(const unsigned int*)(mrow + ktn + 16*t + 4*g) : 0u;
        }
        bf16x8 vf0[4];
#pragma unroll
        for (int nt = 0; nt < 4; ++nt)
            vf0[nt] = *(const bf16x8*)(Vt + kvBase + (size_t)(16*nt + r)*NK_ + kt + 8*g);
        __builtin_amdgcn_sched_barrier(0);

        // ---- logits = mask ? -1e30 : s*0.125*w (prefetched wc/mc) ----
        float lg[16];
#pragma unroll
        for (int t = 0; t < 4; ++t) {
            unsigned int mb[4];
            if (mByte) {
                mb[0] =  mc[t]        & 0xffu;
                mb[1] = (mc[t] >> 8)  & 0xffu;
                mb[2] = (mc[t] >> 16) & 0xffu;
                mb[3] =  mc[t] >> 24;
            } else {
                const uint4 mi = *(const uint4*)(mrow4 + kt + 16*t + 4*g);
                mb[0] = mi.x; mb[1] = mi.y; mb[2] = mi.z; mb[3] = mi.w;
            }
            const float wv[4] = {wc[t].x, wc[t].y, wc[t].z, wc[t].w};
#pragma unroll
            for (int j = 0; j < 4; ++j)
                lg[4*t+j] = mb[j] ? -1e30f : sa[t][j] * 0.125f * wv[j];
        }

        // ---- online softmax ----
        float mx = lg[0];
#pragma unroll
        for (int i2 = 1; i2 < 16; ++i2) mx = fmaxf(mx, lg[i2]);
        mx = fmaxf(mx, __shfl_xor(mx, 16, 64));
        mx = fmaxf(mx, __shfl_xor(mx, 32, 64));
        const float mnew = fmaxf(m_run, mx);
        const float fsc  = __expf(m_run - mnew);
        m_run = mnew;

        float p[16], rs = 0.f;
#pragma unroll
        for (int i2 = 0; i2 < 16; ++i2) { p[i2] = __expf(lg[i2] - mnew); rs += p[i2]; }
        rs += __shfl_xor(rs, 16, 64);
        rs += __shfl_xor(rs, 32, 64);
        l_run = l_run * fsc + rs;

        // ---- pack P -> wave-private swizzled LDS ----
#pragma unroll
        for (int t = 0; t < 4; ++t) {
            const unsigned int w0 = (unsigned int)f2bf(p[4*t+0]) |
                                    ((unsigned int)f2bf(p[4*t+1]) << 16);
            const unsigned int w1 = (unsigned int)f2bf(p[4*t+2]) |
                                    ((unsigned int)f2bf(p[4*t+3]) << 16);
            *(int2*)(pbase + roff + ((32*t + 8*g) ^ sw)) = make_int2((int)w0, (int)w1);
        }
        asm volatile("s_waitcnt lgkmcnt(0)" ::: "memory");
        __builtin_amdgcn_sched_barrier(0);
        const bf16x8 pa0 = *(const bf16x8*)(pbase + roff + ((     16*g) ^ sw));
        const bf16x8 pa1 = *(const bf16x8*)(pbase + roff + ((64 + 16*g) ^ sw));

        // ---- issue V^T s=1 ----
        bf16x8 vf1[4];
#pragma unroll
        for (int nt = 0; nt < 4; ++nt)
            vf1[nt] = *(const bf16x8*)(Vt + kvBase + (size_t)(16*nt + r)*NK_ + kt + 32 + 8*g);

        // ---- rescale O ----
        float fr[4];
#pragma unroll
        for (int j = 0; j < 4; ++j) fr[j] = __shfl(fsc, 4*g + j, 64);
#pragma unroll
        for (int nt = 0; nt < 4; ++nt)
#pragma unroll
            for (int j = 0; j < 4; ++j) oa[nt][j] *= fr[j];

        // ---- O += P.V ----
#pragma unroll
        for (int nt = 0; nt < 4; ++nt) oa[nt] = MFMA16(pa0, vf0[nt], oa[nt]);
#pragma unroll
        for (int nt = 0; nt < 4; ++nt) oa[nt] = MFMA16(pa1, vf1[nt], oa[nt]);

#pragma unroll
        for (int t = 0; t < 4; ++t) { wc[t] = wn[t]; mc[t] = mn[t]; }
        kt += 128;
    }

    // ---- merge the two key phases, then write ----
    __syncthreads();
    if (ph == 1) {
        if (g == 0) { Msh[qg][r] = m_run; Lsh[qg][r] = l_run; }
#pragma unroll
        for (int nt = 0; nt < 4; ++nt)
            *(f32x4*)&Osh[qg][lane][4*nt] = oa[nt];
    }
    __syncthreads();
    if (ph == 0) {
        const float mB = Msh[qg][r], lB = Lsh[qg][r];
        const float mS = fmaxf(m_run, mB);
        const float fA = __expf(m_run - mS);
        const float fB = __expf(mB - mS);
        const float inv = 1.0f / (l_run * fA + lB * fB);
        float frA[4], frB[4], ir[4];
#pragma unroll
        for (int j = 0; j < 4; ++j) {
            frA[j] = __shfl(fA, 4*g + j, 64);
            frB[j] = __shfl(fB, 4*g + j, 64);
            ir[j]  = __shfl(inv, 4*g + j, 64);
        }
        const int bb = bh >> 3, h = bh & 7;
#pragma unroll
        for (int nt = 0; nt < 4; ++nt) {
            const f32x4 ob = *(const f32x4*)&Osh[qg][lane][4*nt];
#pragma unroll
            for (int j = 0; j < 4; ++j) {
                const float val = (oa[nt][j]*frA[j] + ob[j]*frB[j]) * ir[j];
                O[((size_t)(bb*NQ_ + q0 + 4*g + j))*DM_ + h*64 + 16*nt + r] = val;
            }
        }
    }
}

// ---------------------------------------------------------------------------
extern "C" void kernel_launch(void* const* d_in, const int* in_sizes, int n_in,
                              void* d_out, int out_size, void* d_ws, size_t ws_size,
                              hipStream_t stream) {
    (void)in_sizes; (void)n_in; (void)out_size; (void)ws_size;

    const float* q    = (const float*)d_in[0];
    const float* k    = (const float*)d_in[1];
    const float* v    = (const float*)d_in[2];
    const float* attw = (const float*)d_in[3];
    const unsigned char* mask = (const unsigned char*)d_in[4];
    const float* Wq = (const float*)d_in[5];
    const float* bq = (const float*)d_in[6];
    const float* Wk = (const float*)d_in[7];
    const float* bk = (const float*)d_in[8];
    const float* Wv = (const float*)d_in[9];
    const float* bv = (const float*)d_in[10];
    const float* Wo = (const float*)d_in[11];
    const float* bo = (const float*)d_in[12];
    float* out = (float*)d_out;

    // ws layout (ushort elems): q_bf[NE] k_bf[NE] vT[NE] wt[8*WL] | o_ws fp32
    const long long NE = (long long)B_*H_*NQ_*DK_;   // 4Mi
    unsigned short* q_bf = (unsigned short*)d_ws;
    unsigned short* k_bf = q_bf + NE;
    unsigned short* vT   = q_bf + 2*NE;
    unsigned short* wt   = q_bf + 3*NE;
    float*          o_ws = (float*)(wt + 8LL*WL_);

    const dim3 blk(256);
    wprep<<<dim3(8, 8, 4), blk, 0, stream>>>(Wq, Wk, Wv, Wo, wt);

    const dim3 gg(128, 8);
    gemm_split<0><<<gg, blk, 0, stream>>>(q, wt + 0*WL_, wt + 1*WL_, bq, q_bf);
    gemm_split<0><<<gg, blk, 0, stream>>>(k, wt + 2*WL_, wt + 3*WL_, bk, k_bf);
    gemm_split<1><<<gg, blk, 0, stream>>>(v, wt + 4*WL_, wt + 5*WL_, bv, vT);

    attn_mfma<<<dim3(NQ_/32, B_*H_), blk, 0, stream>>>(q_bf, k_bf, vT, attw, mask, o_ws);

    gemm_split<2><<<gg, blk, 0, stream>>>(o_ws, wt + 6*WL_, wt + 7*WL_, bo, out);
}

// Round 5
// 544.960 us; speedup vs baseline: 8.3087x; 1.1071x over previous
//
#include <hip/hip_runtime.h>
#include <hip/hip_bf16.h>
#include <math.h>

#define B_   4
#define H_   8
#define NQ_  2048
#define NK_  2048
#define DM_  512
#define DK_  64
#define WL_  262144   // 512*512

typedef short  bf16x8 __attribute__((ext_vector_type(8)));
typedef float  f32x4  __attribute__((ext_vector_type(4)));

static __device__ __forceinline__ f32x4 MFMA16(bf16x8 a, bf16x8 b, f32x4 c) {
    return __builtin_amdgcn_mfma_f32_16x16x32_bf16(a, b, c, 0, 0, 0);
}
static __device__ __forceinline__ unsigned short f2bf(float f) {
    __hip_bfloat16 h = __float2bfloat16(f);
    unsigned short u; __builtin_memcpy(&u, &h, 2); return u;
}
static __device__ __forceinline__ float bf2f(unsigned short u) {
    unsigned int x = ((unsigned int)u) << 16;
    float f; __builtin_memcpy(&f, &x, 4); return f;
}
static __device__ __forceinline__ void glds16(const void* g, void* l) {
    __builtin_amdgcn_global_load_lds(
        (__attribute__((address_space(1))) const void*)g,
        (__attribute__((address_space(3))) void*)l, 16, 0, 0);
}

// ---------------------------------------------------------------------------
// mask (bool-byte or 4-byte 0/1|1.0f) -> bitmask, 64 elems per thread
// ---------------------------------------------------------------------------
__global__ __launch_bounds__(256) void conv_mask(const unsigned char* __restrict__ Mk,
                                                 unsigned long long* __restrict__ bits)
{
    __shared__ int s_flag;
    const int tid = threadIdx.x;
    if (tid == 0) s_flag = 0;
    __syncthreads();
    {
        bool any = false;
#pragma unroll
        for (int i = 1; i < 16; i += 4)
            if (Mk[tid*16 + i]) any = true;
        if (any) s_flag = 1;
    }
    __syncthreads();
    const long long gid = (long long)blockIdx.x * 256 + tid;
    unsigned long long m = 0ull;
    if (s_flag) {            // 1-byte mask
        const uint4* p = (const uint4*)(Mk + gid * 64);
#pragma unroll
        for (int c = 0; c < 4; ++c) {
            const uint4 u = p[c];
            const unsigned int w[4] = {u.x, u.y, u.z, u.w};
#pragma unroll
            for (int j = 0; j < 4; ++j)
#pragma unroll
                for (int b = 0; b < 4; ++b)
                    if ((w[j] >> (8*b)) & 0xffu) m |= 1ull << (c*16 + j*4 + b);
        }
    } else {                 // 4-byte mask
        const uint4* p = (const uint4*)Mk + gid * 16;
#pragma unroll
        for (int c = 0; c < 16; ++c) {
            const uint4 u = p[c];
            if (u.x) m |= 1ull << (c*4 + 0);
            if (u.y) m |= 1ull << (c*4 + 1);
            if (u.z) m |= 1ull << (c*4 + 2);
            if (u.w) m |= 1ull << (c*4 + 3);
        }
    }
    bits[gid] = m;
}

// ---------------------------------------------------------------------------
// W (512x512 fp32, [k][n]) -> WT_hi/WT_lo (bf16, [n][k]) for all 4 weights
// ---------------------------------------------------------------------------
__global__ __launch_bounds__(256) void wprep(const float* __restrict__ Wq,
                                             const float* __restrict__ Wk,
                                             const float* __restrict__ Wv,
                                             const float* __restrict__ Wo,
                                             unsigned short* __restrict__ out)
{
    __shared__ float tile[64][65];
    const int tid = threadIdx.x;
    const int k0 = blockIdx.x * 64, n0 = blockIdx.y * 64, w = blockIdx.z;
    const float* W = (w == 0) ? Wq : (w == 1) ? Wk : (w == 2) ? Wv : Wo;
    unsigned short* WTh = out + (size_t)w * 2 * WL_;
    unsigned short* WTl = WTh + WL_;

#pragma unroll
    for (int rd = 0; rd < 4; ++rd) {
        const int k = (tid >> 4) + 16*rd, c4 = (tid & 15) * 4;
        const float4 v4 = *(const float4*)(W + (size_t)(k0 + k)*DM_ + n0 + c4);
        tile[k][c4+0] = v4.x; tile[k][c4+1] = v4.y;
        tile[k][c4+2] = v4.z; tile[k][c4+3] = v4.w;
    }
    __syncthreads();
#pragma unroll
    for (int rd = 0; rd < 4; ++rd) {
        const int n = (tid >> 4) + 16*rd, kk = (tid & 15) * 4;
        unsigned short hh[4], ll[4];
#pragma unroll
        for (int j = 0; j < 4; ++j) {
            const float f = tile[kk + j][n];
            hh[j] = f2bf(f);
            ll[j] = f2bf(f - bf2f(hh[j]));
        }
        *(ushort4*)(WTh + (size_t)(n0 + n)*DM_ + k0 + kk) = make_ushort4(hh[0],hh[1],hh[2],hh[3]);
        *(ushort4*)(WTl + (size_t)(n0 + n)*DM_ + k0 + kk) = make_ushort4(ll[0],ll[1],ll[2],ll[3]);
    }
}

// ---------------------------------------------------------------------------
// Split-bf16 MFMA GEMM: C = A(fp32) @ W + bias (x oscale), 3-term split.
// MODE 0: bf16 out, (B,H,N,64) layout   MODE 1: bf16 out, (B,H,64,NK) (V^T)
// MODE 2: fp32 out, row-major MxDM
// ---------------------------------------------------------------------------
template<int MODE>
__global__ __launch_bounds__(256) void gemm_split(
    const float* __restrict__ A,
    const unsigned short* __restrict__ WTh,
    const unsigned short* __restrict__ WTl,
    const float* __restrict__ bias,
    void* __restrict__ outv, const float oscale)
{
    __shared__ unsigned short Ah[64][64], Al[64][64], Bh[64][64], Bl[64][64];

    const int tid = threadIdx.x;
    const int w = tid >> 6, lane = tid & 63, g = lane >> 4, r = lane & 15;
    const int m0 = blockIdx.x * 64, n0 = blockIdx.y * 64;

    char* pAh = (char*)&Ah[0][0];
    char* pAl = (char*)&Al[0][0];
    char* pBh = (char*)&Bh[0][0];
    char* pBl = (char*)&Bl[0][0];

    const f32x4 z4 = {0.f, 0.f, 0.f, 0.f};
    f32x4 acc[4] = {z4, z4, z4, z4};

    for (int kt = 0; kt < DM_; kt += 64) {
#pragma unroll
        for (int rd = 0; rd < 4; ++rd) {
            const int row = (tid >> 4) + 16*rd;
            const int c4  = (tid & 15) * 4;
            const float4 a4 = *(const float4*)(A + (size_t)(m0 + row)*DM_ + kt + c4);
            const float av[4] = {a4.x, a4.y, a4.z, a4.w};
            unsigned short hh[4], ll[4];
#pragma unroll
            for (int j = 0; j < 4; ++j) {
                hh[j] = f2bf(av[j]);
                ll[j] = f2bf(av[j] - bf2f(hh[j]));
            }
            const int bo = (c4 * 2) ^ ((row & 7) << 4);
            *(ushort4*)(pAh + row*128 + bo) = make_ushort4(hh[0],hh[1],hh[2],hh[3]);
            *(ushort4*)(pAl + row*128 + bo) = make_ushort4(ll[0],ll[1],ll[2],ll[3]);
        }
#pragma unroll
        for (int rd = 0; rd < 2; ++rd) {
            const int idx = tid + 256*rd;
            const int row = idx >> 3;
            const int cb  = (idx & 7) * 16;
            const int bo  = cb ^ ((row & 7) << 4);
            const size_t goff = (size_t)(n0 + row)*DM_ + kt + (cb >> 1);
            *(bf16x8*)(pBh + row*128 + bo) = *(const bf16x8*)(WTh + goff);
            *(bf16x8*)(pBl + row*128 + bo) = *(const bf16x8*)(WTl + goff);
        }
        __syncthreads();

        const int swr = (r & 7) << 4;
#pragma unroll
        for (int ks = 0; ks < 2; ++ks) {
            const int xo = (64*ks + 16*g) ^ swr;
            const bf16x8 xh = *(const bf16x8*)(pAh + (16*w + r)*128 + xo);
            const bf16x8 xl = *(const bf16x8*)(pAl + (16*w + r)*128 + xo);
#pragma unroll
            for (int nt = 0; nt < 4; ++nt) {
                const bf16x8 bh = *(const bf16x8*)(pBh + (16*nt + r)*128 + xo);
                const bf16x8 bl = *(const bf16x8*)(pBl + (16*nt + r)*128 + xo);
                if (MODE == 1) {
                    acc[nt] = MFMA16(xh, bh, acc[nt]);
                    acc[nt] = MFMA16(xh, bl, acc[nt]);
                    acc[nt] = MFMA16(xl, bh, acc[nt]);
                } else {
                    acc[nt] = MFMA16(bh, xh, acc[nt]);
                    acc[nt] = MFMA16(bh, xl, acc[nt]);
                    acc[nt] = MFMA16(bl, xh, acc[nt]);
                }
            }
        }
        __syncthreads();
    }

    if (MODE == 0) {
        const int m = m0 + 16*w + r;
        const int b = m >> 11, q = m & 2047, h = blockIdx.y;
        unsigned short* dst = (unsigned short*)outv + (((size_t)(b*H_ + h))*NQ_ + q)*DK_;
#pragma unroll
        for (int nt = 0; nt < 4; ++nt) {
            unsigned short u[4];
#pragma unroll
            for (int j = 0; j < 4; ++j)
                u[j] = f2bf((acc[nt][j] + bias[n0 + 16*nt + 4*g + j]) * oscale);
            *(ushort4*)(dst + 16*nt + 4*g) = make_ushort4(u[0],u[1],u[2],u[3]);
        }
    } else if (MODE == 1) {
        const int b = m0 >> 11, h = blockIdx.y;
        const int key = (m0 & 2047) + 16*w + 4*g;
#pragma unroll
        for (int nt = 0; nt < 4; ++nt) {
            const int dv = 16*nt + r;
            const float bv = bias[n0 + dv];
            unsigned short u[4];
#pragma unroll
            for (int j = 0; j < 4; ++j) u[j] = f2bf(acc[nt][j] + bv);
            *(ushort4*)((unsigned short*)outv +
                        (((size_t)(b*H_ + h))*DK_ + dv)*NK_ + key) = make_ushort4(u[0],u[1],u[2],u[3]);
        }
    } else {
        const int m = m0 + 16*w + r;
        float* dst = (float*)outv + (size_t)m*DM_ + n0;
#pragma unroll
        for (int nt = 0; nt < 4; ++nt) {
            float4 o4;
            o4.x = acc[nt][0] + bias[n0 + 16*nt + 4*g + 0];
            o4.y = acc[nt][1] + bias[n0 + 16*nt + 4*g + 1];
            o4.z = acc[nt][2] + bias[n0 + 16*nt + 4*g + 2];
            o4.w = acc[nt][3] + bias[n0 + 16*nt + 4*g + 3];
            *(float4*)(dst + 16*nt + 4*g) = o4;
        }
    }
}

// ---------------------------------------------------------------------------
// MFMA flash attention. 4 waves = 4 q-subblocks of 16 rows; K-step 64.
// W staged via global_load_lds into wave-private swizzled LDS slices,
// double-buffered; K prefetched one step ahead in regs; bitmask for mask.
// FIFO issue order [V | stageW | bits | K] -> counted vmcnt keeps the
// next-step prefetch in flight. No block barriers in the main loop.
// ---------------------------------------------------------------------------
__global__ __launch_bounds__(256) void attn_mfma(
    const unsigned short* __restrict__ Qb,
    const unsigned short* __restrict__ Kb,
    const unsigned short* __restrict__ Vt,
    const float* __restrict__ Wt,
    const unsigned long long* __restrict__ Mb,
    float* __restrict__ O)
{
    __shared__ float Wlds[2][4][1024];   // [buf][wave][16 rows x 64 cols] swizzled
    __shared__ short Pl[4][1024];        // P bounce, 2KB/wave

    const int tid  = threadIdx.x;
    const int wv   = tid >> 6, lane = tid & 63;
    const int g    = lane >> 4, r = lane & 15;
    const int q0   = blockIdx.x * 64 + wv * 16;   // wave's first q-row
    const int bh   = blockIdx.y;

    const size_t kvBase = (size_t)bh * NK_ * DK_;
    const unsigned short* qp = Qb + kvBase + (size_t)(q0 + r)*DK_ + 8*g;
    const bf16x8 qf0 = *(const bf16x8*)qp;
    const bf16x8 qf1 = *(const bf16x8*)(qp + 32);

    const float* wrow_base = Wt + ((size_t)bh*NQ_ + q0)*NK_;
    const unsigned long long* brow = Mb + ((size_t)bh*NQ_ + q0 + r)*(NK_/64);

    const f32x4 zero4 = {0.f, 0.f, 0.f, 0.f};
    f32x4 oa[4] = {zero4, zero4, zero4, zero4};
    float m_run = -1e30f, l_run = 0.f;

    char* pbase = (char*)&Pl[wv][0];
    const int roff = r * 128;
    const int sw   = (r & 7) << 4;

    // wave-private W stage: 4 glds calls, 1KB each (4 rows x 256B contiguous),
    // source pre-swizzled so LDS-linear == swizzled layout
    auto stage = [&](int buf, int kt) {
        float* base = &Wlds[buf][wv][0];
#pragma unroll
        for (int c = 0; c < 4; ++c) {
            const int row = c*4 + (lane >> 4);
            const int blk = (lane & 15) ^ (row & 7);
            glds16(wrow_base + (size_t)row*NK_ + kt + blk*4, base + c*256 + lane*4);
        }
    };
    auto loadK = [&](int kt, bf16x8* kf) {
#pragma unroll
        for (int t = 0; t < 4; ++t) {
            const unsigned short* kp = Kb + kvBase + (size_t)(kt + 16*t + r)*DK_ + 8*g;
            kf[2*t]   = *(const bf16x8*)kp;
            kf[2*t+1] = *(const bf16x8*)(kp + 32);
        }
    };

    auto body = [&](int i, int p, bf16x8* kcur, bf16x8* knxt,
                    unsigned long long bcur, unsigned long long* bnxt) {
        const int kt = i * 64;
        // ---- issue V (consumed at PV this iter) ----
        bf16x8 vf[8];
#pragma unroll
        for (int s = 0; s < 2; ++s)
#pragma unroll
            for (int nt = 0; nt < 4; ++nt)
                vf[4*s+nt] = *(const bf16x8*)(Vt + kvBase +
                                (size_t)(16*nt + r)*NK_ + kt + 32*s + 8*g);
        __builtin_amdgcn_sched_barrier(0);
        // ---- issue next-step prefetches: W-stage, bits, K ----
        const int ktn = (kt + 64 < NK_) ? kt + 64 : kt;
        stage(p^1, ktn);
        *bnxt = brow[ktn >> 6];
        loadK(ktn, knxt);
        __builtin_amdgcn_sched_barrier(0);

        // ---- QK MFMA (kcur loaded one step ago) ----
        f32x4 sa[4] = {zero4, zero4, zero4, zero4};
        __builtin_amdgcn_s_setprio(1);
#pragma unroll
        for (int t = 0; t < 4; ++t) {
            sa[t] = MFMA16(kcur[2*t],   qf0, sa[t]);
            sa[t] = MFMA16(kcur[2*t+1], qf1, sa[t]);
        }
        __builtin_amdgcn_s_setprio(0);
        __builtin_amdgcn_sched_barrier(0);
        // drain this step's W-stage (older than kcur's wait) + V; keep 13
        // (= stageW4 + bits1 + K8 next-step prefetch) in flight
        asm volatile("s_waitcnt vmcnt(13)" ::: "memory");
        __builtin_amdgcn_sched_barrier(0);

        // ---- W fragments from swizzled LDS ----
        const float* wb = &Wlds[p][wv][0];
        float4 wfr[4];
#pragma unroll
        for (int t = 0; t < 4; ++t)
            wfr[t] = *(const float4*)(wb + r*64 + ((((4*t + g) ^ (r & 7)) << 2)));

        // ---- logits = maskbit ? -1e30 : s * w  (0.125 folded into Q) ----
        float lg[16];
#pragma unroll
        for (int t = 0; t < 4; ++t) {
            const unsigned int half = (t & 2) ? (unsigned int)(bcur >> 32)
                                              : (unsigned int)bcur;
            const float wv4[4] = {wfr[t].x, wfr[t].y, wfr[t].z, wfr[t].w};
#pragma unroll
            for (int j = 0; j < 4; ++j) {
                const unsigned int bit = (half >> (16*(t & 1) + 4*g + j)) & 1u;
                lg[4*t+j] = bit ? -1e30f : sa[t][j] * wv4[j];
            }
        }

        // ---- online softmax ----
        float mx = lg[0];
#pragma unroll
        for (int i2 = 1; i2 < 16; ++i2) mx = fmaxf(mx, lg[i2]);
        mx = fmaxf(mx, __shfl_xor(mx, 16, 64));
        mx = fmaxf(mx, __shfl_xor(mx, 32, 64));
        const float mnew = fmaxf(m_run, mx);
        const float fsc  = __expf(m_run - mnew);
        m_run = mnew;
        float p16[16], rs = 0.f;
#pragma unroll
        for (int i2 = 0; i2 < 16; ++i2) { p16[i2] = __expf(lg[i2] - mnew); rs += p16[i2]; }
        rs += __shfl_xor(rs, 16, 64);
        rs += __shfl_xor(rs, 32, 64);
        l_run = l_run * fsc + rs;

        // ---- pack P -> wave-private swizzled LDS ----
#pragma unroll
        for (int t = 0; t < 4; ++t) {
            const unsigned int w0 = (unsigned int)f2bf(p16[4*t+0]) |
                                    ((unsigned int)f2bf(p16[4*t+1]) << 16);
            const unsigned int w1 = (unsigned int)f2bf(p16[4*t+2]) |
                                    ((unsigned int)f2bf(p16[4*t+3]) << 16);
            *(int2*)(pbase + roff + ((32*t + 8*g) ^ sw)) = make_int2((int)w0, (int)w1);
        }
        asm volatile("s_waitcnt lgkmcnt(0)" ::: "memory");
        __builtin_amdgcn_sched_barrier(0);
        const bf16x8 pa0 = *(const bf16x8*)(pbase + roff + ((     16*g) ^ sw));
        const bf16x8 pa1 = *(const bf16x8*)(pbase + roff + ((64 + 16*g) ^ sw));

        // ---- rescale O ----
        float fr[4];
#pragma unroll
        for (int j = 0; j < 4; ++j) fr[j] = __shfl(fsc, 4*g + j, 64);
#pragma unroll
        for (int nt = 0; nt < 4; ++nt)
#pragma unroll
            for (int j = 0; j < 4; ++j) oa[nt][j] *= fr[j];

        // ---- O += P.V ----
        __builtin_amdgcn_s_setprio(1);
#pragma unroll
        for (int nt = 0; nt < 4; ++nt) oa[nt] = MFMA16(pa0, vf[nt],   oa[nt]);
#pragma unroll
        for (int nt = 0; nt < 4; ++nt) oa[nt] = MFMA16(pa1, vf[4+nt], oa[nt]);
        __builtin_amdgcn_s_setprio(0);
    };

    // ---- prologue: stage step 0 ----
    bf16x8 kA[8], kB[8];
    unsigned long long bA, bB;
    stage(0, 0);
    bA = brow[0];
    loadK(0, kA);

#pragma unroll 1
    for (int i = 0; i < 32; i += 2) {
        body(i,     0, kA, kB, bA, &bB);
        body(i + 1, 1, kB, kA, bB, &bA);
    }

    // ---- epilogue: normalize + write (b, q, h*64+dv) fp32 ----
    const float inv = 1.0f / l_run;
    float ir[4];
#pragma unroll
    for (int j = 0; j < 4; ++j) ir[j] = __shfl(inv, 4*g + j, 64);
    const int bb = bh >> 3, h = bh & 7;
#pragma unroll
    for (int nt = 0; nt < 4; ++nt)
#pragma unroll
        for (int j = 0; j < 4; ++j)
            O[((size_t)(bb*NQ_ + q0 + 4*g + j))*DM_ + h*64 + 16*nt + r] = oa[nt][j] * ir[j];
}

// ---------------------------------------------------------------------------
extern "C" void kernel_launch(void* const* d_in, const int* in_sizes, int n_in,
                              void* d_out, int out_size, void* d_ws, size_t ws_size,
                              hipStream_t stream) {
    (void)in_sizes; (void)n_in; (void)out_size; (void)ws_size;

    const float* q    = (const float*)d_in[0];
    const float* k    = (const float*)d_in[1];
    const float* v    = (const float*)d_in[2];
    const float* attw = (const float*)d_in[3];
    const unsigned char* mask = (const unsigned char*)d_in[4];
    const float* Wq = (const float*)d_in[5];
    const float* bq = (const float*)d_in[6];
    const float* Wk = (const float*)d_in[7];
    const float* bk = (const float*)d_in[8];
    const float* Wv = (const float*)d_in[9];
    const float* bv = (const float*)d_in[10];
    const float* Wo = (const float*)d_in[11];
    const float* bo = (const float*)d_in[12];
    float* out = (float*)d_out;

    // ws (shorts): q_bf[NE] k_bf[NE] vT[NE] wt[8*WL] | bits[2Mi u64] | o_ws fp32
    const long long NE = (long long)B_*H_*NQ_*DK_;        // 4Mi
    unsigned short* q_bf = (unsigned short*)d_ws;
    unsigned short* k_bf = q_bf + NE;
    unsigned short* vT   = q_bf + 2*NE;
    unsigned short* wt   = q_bf + 3*NE;
    unsigned long long* bits = (unsigned long long*)(wt + 8LL*WL_);
    const long long NB = (long long)B_*H_*NQ_*NK_/64;     // 2Mi
    float* o_ws = (float*)(bits + NB);

    const dim3 blk(256);
    wprep<<<dim3(8, 8, 4), blk, 0, stream>>>(Wq, Wk, Wv, Wo, wt);
    conv_mask<<<dim3((int)(NB/256)), blk, 0, stream>>>(mask, bits);

    const dim3 gg(128, 8);
    gemm_split<0><<<gg, blk, 0, stream>>>(q, wt + 0*WL_, wt + 1*WL_, bq, q_bf, 0.125f);
    gemm_split<0><<<gg, blk, 0, stream>>>(k, wt + 2*WL_, wt + 3*WL_, bk, k_bf, 1.0f);
    gemm_split<1><<<gg, blk, 0, stream>>>(v, wt + 4*WL_, wt + 5*WL_, bv, vT, 1.0f);

    attn_mfma<<<dim3(NQ_/64, B_*H_), blk, 0, stream>>>(q_bf, k_bf, vT, attw, bits, o_ws);

    gemm_split<2><<<gg, blk, 0, stream>>>(o_ws, wt + 6*WL_, wt + 7*WL_, bo, out, 1.0f);
}

// Round 6
// 542.984 us; speedup vs baseline: 8.3389x; 1.0036x over previous
//
#include <hip/hip_runtime.h>
#include <hip/hip_bf16.h>
#include <math.h>

#define B_   4
#define H_   8
#define NQ_  2048
#define NK_  2048
#define DM_  512
#define DK_  64
#define WL_  262144   // 512*512

typedef short  bf16x8 __attribute__((ext_vector_type(8)));
typedef float  f32x4  __attribute__((ext_vector_type(4)));

static __device__ __forceinline__ f32x4 MFMA16(bf16x8 a, bf16x8 b, f32x4 c) {
    return __builtin_amdgcn_mfma_f32_16x16x32_bf16(a, b, c, 0, 0, 0);
}
static __device__ __forceinline__ unsigned short f2bf(float f) {
    __hip_bfloat16 h = __float2bfloat16(f);
    unsigned short u; __builtin_memcpy(&u, &h, 2); return u;
}
static __device__ __forceinline__ float bf2f(unsigned short u) {
    unsigned int x = ((unsigned int)u) << 16;
    float f; __builtin_memcpy(&f, &x, 4); return f;
}
static __device__ __forceinline__ void glds16(const void* g, void* l) {
    __builtin_amdgcn_global_load_lds(
        (__attribute__((address_space(1))) const void*)g,
        (__attribute__((address_space(3))) void*)l, 16, 0, 0);
}

// ---------------------------------------------------------------------------
// mask (bool-byte or 4-byte 0/1|1.0f) -> bitmask, 64 elems per thread
// ---------------------------------------------------------------------------
__global__ __launch_bounds__(256) void conv_mask(const unsigned char* __restrict__ Mk,
                                                 unsigned long long* __restrict__ bits)
{
    __shared__ int s_flag;
    const int tid = threadIdx.x;
    if (tid == 0) s_flag = 0;
    __syncthreads();
    {
        bool any = false;
#pragma unroll
        for (int i = 1; i < 16; i += 4)
            if (Mk[tid*16 + i]) any = true;
        if (any) s_flag = 1;
    }
    __syncthreads();
    const long long gid = (long long)blockIdx.x * 256 + tid;
    unsigned long long m = 0ull;
    if (s_flag) {            // 1-byte mask
        const uint4* p = (const uint4*)(Mk + gid * 64);
#pragma unroll
        for (int c = 0; c < 4; ++c) {
            const uint4 u = p[c];
            const unsigned int w[4] = {u.x, u.y, u.z, u.w};
#pragma unroll
            for (int j = 0; j < 4; ++j)
#pragma unroll
                for (int b = 0; b < 4; ++b)
                    if ((w[j] >> (8*b)) & 0xffu) m |= 1ull << (c*16 + j*4 + b);
        }
    } else {                 // 4-byte mask
        const uint4* p = (const uint4*)Mk + gid * 16;
#pragma unroll
        for (int c = 0; c < 16; ++c) {
            const uint4 u = p[c];
            if (u.x) m |= 1ull << (c*4 + 0);
            if (u.y) m |= 1ull << (c*4 + 1);
            if (u.z) m |= 1ull << (c*4 + 2);
            if (u.w) m |= 1ull << (c*4 + 3);
        }
    }
    bits[gid] = m;
}

// ---------------------------------------------------------------------------
// W (512x512 fp32, [k][n]) -> WT_hi/WT_lo (bf16, [n][k]) for all 4 weights
// ---------------------------------------------------------------------------
__global__ __launch_bounds__(256) void wprep(const float* __restrict__ Wq,
                                             const float* __restrict__ Wk,
                                             const float* __restrict__ Wv,
                                             const float* __restrict__ Wo,
                                             unsigned short* __restrict__ out)
{
    __shared__ float tile[64][65];
    const int tid = threadIdx.x;
    const int k0 = blockIdx.x * 64, n0 = blockIdx.y * 64, w = blockIdx.z;
    const float* W = (w == 0) ? Wq : (w == 1) ? Wk : (w == 2) ? Wv : Wo;
    unsigned short* WTh = out + (size_t)w * 2 * WL_;
    unsigned short* WTl = WTh + WL_;

#pragma unroll
    for (int rd = 0; rd < 4; ++rd) {
        const int k = (tid >> 4) + 16*rd, c4 = (tid & 15) * 4;
        const float4 v4 = *(const float4*)(W + (size_t)(k0 + k)*DM_ + n0 + c4);
        tile[k][c4+0] = v4.x; tile[k][c4+1] = v4.y;
        tile[k][c4+2] = v4.z; tile[k][c4+3] = v4.w;
    }
    __syncthreads();
#pragma unroll
    for (int rd = 0; rd < 4; ++rd) {
        const int n = (tid >> 4) + 16*rd, kk = (tid & 15) * 4;
        unsigned short hh[4], ll[4];
#pragma unroll
        for (int j = 0; j < 4; ++j) {
            const float f = tile[kk + j][n];
            hh[j] = f2bf(f);
            ll[j] = f2bf(f - bf2f(hh[j]));
        }
        *(ushort4*)(WTh + (size_t)(n0 + n)*DM_ + k0 + kk) = make_ushort4(hh[0],hh[1],hh[2],hh[3]);
        *(ushort4*)(WTl + (size_t)(n0 + n)*DM_ + k0 + kk) = make_ushort4(ll[0],ll[1],ll[2],ll[3]);
    }
}

// ---------------------------------------------------------------------------
// Split-bf16 MFMA GEMM: C = A(fp32) @ W + bias (x oscale).
// MODE 0/1: 2-term (Ah*Wh + Ah*Wl) -> bf16 out (error ~ bf16 rounding).
// MODE 2:   3-term (+ Al*Wh)       -> fp32 out (final projection).
// MODE 0: (B,H,N,64) layout  MODE 1: (B,H,64,NK) (V^T)  MODE 2: row-major
// ---------------------------------------------------------------------------
template<int MODE>
__global__ __launch_bounds__(256) void gemm_split(
    const float* __restrict__ A,
    const unsigned short* __restrict__ WTh,
    const unsigned short* __restrict__ WTl,
    const float* __restrict__ bias,
    void* __restrict__ outv, const float oscale)
{
    __shared__ unsigned short Ah[64][64], Al[64][64], Bh[64][64], Bl[64][64];

    const int tid = threadIdx.x;
    const int w = tid >> 6, lane = tid & 63, g = lane >> 4, r = lane & 15;
    const int m0 = blockIdx.x * 64, n0 = blockIdx.y * 64;

    char* pAh = (char*)&Ah[0][0];
    char* pAl = (char*)&Al[0][0];
    char* pBh = (char*)&Bh[0][0];
    char* pBl = (char*)&Bl[0][0];

    const f32x4 z4 = {0.f, 0.f, 0.f, 0.f};
    f32x4 acc[4] = {z4, z4, z4, z4};

    for (int kt = 0; kt < DM_; kt += 64) {
#pragma unroll
        for (int rd = 0; rd < 4; ++rd) {
            const int row = (tid >> 4) + 16*rd;
            const int c4  = (tid & 15) * 4;
            const float4 a4 = *(const float4*)(A + (size_t)(m0 + row)*DM_ + kt + c4);
            const float av[4] = {a4.x, a4.y, a4.z, a4.w};
            unsigned short hh[4];
#pragma unroll
            for (int j = 0; j < 4; ++j) hh[j] = f2bf(av[j]);
            const int bo = (c4 * 2) ^ ((row & 7) << 4);
            *(ushort4*)(pAh + row*128 + bo) = make_ushort4(hh[0],hh[1],hh[2],hh[3]);
            if (MODE == 2) {
                unsigned short ll[4];
#pragma unroll
                for (int j = 0; j < 4; ++j) ll[j] = f2bf(av[j] - bf2f(hh[j]));
                *(ushort4*)(pAl + row*128 + bo) = make_ushort4(ll[0],ll[1],ll[2],ll[3]);
            }
        }
#pragma unroll
        for (int rd = 0; rd < 2; ++rd) {
            const int idx = tid + 256*rd;
            const int row = idx >> 3;
            const int cb  = (idx & 7) * 16;
            const int bo  = cb ^ ((row & 7) << 4);
            const size_t goff = (size_t)(n0 + row)*DM_ + kt + (cb >> 1);
            *(bf16x8*)(pBh + row*128 + bo) = *(const bf16x8*)(WTh + goff);
            *(bf16x8*)(pBl + row*128 + bo) = *(const bf16x8*)(WTl + goff);
        }
        __syncthreads();

        const int swr = (r & 7) << 4;
#pragma unroll
        for (int ks = 0; ks < 2; ++ks) {
            const int xo = (64*ks + 16*g) ^ swr;
            const bf16x8 xh = *(const bf16x8*)(pAh + (16*w + r)*128 + xo);
#pragma unroll
            for (int nt = 0; nt < 4; ++nt) {
                const bf16x8 bh = *(const bf16x8*)(pBh + (16*nt + r)*128 + xo);
                const bf16x8 bl = *(const bf16x8*)(pBl + (16*nt + r)*128 + xo);
                if (MODE == 1) {
                    acc[nt] = MFMA16(xh, bh, acc[nt]);
                    acc[nt] = MFMA16(xh, bl, acc[nt]);
                } else if (MODE == 0) {
                    acc[nt] = MFMA16(bh, xh, acc[nt]);
                    acc[nt] = MFMA16(bl, xh, acc[nt]);
                } else {
                    const bf16x8 xl = *(const bf16x8*)(pAl + (16*w + r)*128 + xo);
                    acc[nt] = MFMA16(bh, xh, acc[nt]);
                    acc[nt] = MFMA16(bh, xl, acc[nt]);
                    acc[nt] = MFMA16(bl, xh, acc[nt]);
                }
            }
        }
        __syncthreads();
    }

    if (MODE == 0) {
        const int m = m0 + 16*w + r;
        const int b = m >> 11, q = m & 2047, h = blockIdx.y;
        unsigned short* dst = (unsigned short*)outv + (((size_t)(b*H_ + h))*NQ_ + q)*DK_;
#pragma unroll
        for (int nt = 0; nt < 4; ++nt) {
            unsigned short u[4];
#pragma unroll
            for (int j = 0; j < 4; ++j)
                u[j] = f2bf((acc[nt][j] + bias[n0 + 16*nt + 4*g + j]) * oscale);
            *(ushort4*)(dst + 16*nt + 4*g) = make_ushort4(u[0],u[1],u[2],u[3]);
        }
    } else if (MODE == 1) {
        const int b = m0 >> 11, h = blockIdx.y;
        const int key = (m0 & 2047) + 16*w + 4*g;
#pragma unroll
        for (int nt = 0; nt < 4; ++nt) {
            const int dv = 16*nt + r;
            const float bv = bias[n0 + dv];
            unsigned short u[4];
#pragma unroll
            for (int j = 0; j < 4; ++j) u[j] = f2bf(acc[nt][j] + bv);
            *(ushort4*)((unsigned short*)outv +
                        (((size_t)(b*H_ + h))*DK_ + dv)*NK_ + key) = make_ushort4(u[0],u[1],u[2],u[3]);
        }
    } else {
        const int m = m0 + 16*w + r;
        float* dst = (float*)outv + (size_t)m*DM_ + n0;
#pragma unroll
        for (int nt = 0; nt < 4; ++nt) {
            float4 o4;
            o4.x = acc[nt][0] + bias[n0 + 16*nt + 4*g + 0];
            o4.y = acc[nt][1] + bias[n0 + 16*nt + 4*g + 1];
            o4.z = acc[nt][2] + bias[n0 + 16*nt + 4*g + 2];
            o4.w = acc[nt][3] + bias[n0 + 16*nt + 4*g + 3];
            *(float4*)(dst + 16*nt + 4*g) = o4;
        }
    }
}

// ---------------------------------------------------------------------------
// MFMA flash attention. 4 waves = 4 q-subblocks of 16 rows; K-step 64.
// All fragments in NAMED registers (no arrays-through-pointers -> no scratch).
// Pipeline per iter i (FIFO pinned by sched_barriers):
//   QK(i) [auto-wait drains stage(i)] -> issue stage(i+1),bits(i+1),K(i+1)
//   -> W-frags from LDS, softmax, P-pack -> PV(i) [auto-wait keeps 13 in
//   flight] -> issue V(i+1).
// ---------------------------------------------------------------------------
__global__ __launch_bounds__(256) void attn_mfma(
    const unsigned short* __restrict__ Qb,
    const unsigned short* __restrict__ Kb,
    const unsigned short* __restrict__ Vt,
    const float* __restrict__ Wt,
    const unsigned long long* __restrict__ Mb,
    float* __restrict__ O)
{
    __shared__ float Wlds[2][4][1024];   // [buf][wave][16 rows x 64 cols] swizzled
    __shared__ short Pl[4][1024];        // P bounce, 2KB/wave

    const int tid  = threadIdx.x;
    const int wv   = tid >> 6, lane = tid & 63;
    const int g    = lane >> 4, r = lane & 15;
    const int q0   = blockIdx.x * 64 + wv * 16;
    const int bh   = blockIdx.y;

    const size_t kvBase = (size_t)bh * NK_ * DK_;
    const unsigned short* qp = Qb + kvBase + (size_t)(q0 + r)*DK_ + 8*g;
    const bf16x8 qf0 = *(const bf16x8*)qp;
    const bf16x8 qf1 = *(const bf16x8*)(qp + 32);

    const float* wrow_base = Wt + ((size_t)bh*NQ_ + q0)*NK_;
    const unsigned long long* brow = Mb + ((size_t)bh*NQ_ + q0 + r)*(NK_/64);
    const unsigned short* kbase = Kb + kvBase + (size_t)r*DK_ + 8*g;
    const unsigned short* vbase = Vt + kvBase + (size_t)r*NK_ + 8*g;

    const f32x4 zero4 = {0.f, 0.f, 0.f, 0.f};
    f32x4 oa0 = zero4, oa1 = zero4, oa2 = zero4, oa3 = zero4;
    float m_run = -1e30f, l_run = 0.f;

    char* pbase = (char*)&Pl[wv][0];
    const int roff = r * 128;
    const int sw   = (r & 7) << 4;

    auto stage = [&](int buf, int kt) {
        float* base = &Wlds[buf][wv][0];
#pragma unroll
        for (int c = 0; c < 4; ++c) {
            const int row = c*4 + (lane >> 4);
            const int blk = (lane & 15) ^ (row & 7);
            glds16(wrow_base + (size_t)row*NK_ + kt + blk*4, base + c*256 + lane*4);
        }
    };

    // K fragments: k{t}{s} = K[kt + 16t + r][32s + 8g ..], V: v{s}{nt}
    bf16x8 k00,k01,k10,k11,k20,k21,k30,k31;
    bf16x8 v00,v01,v02,v03, v10,v11,v12,v13;

#define LOADK(ktv) do { \
    const unsigned short* kp_ = kbase + (size_t)(ktv)*DK_;      \
    k00 = *(const bf16x8*)kp_;         k01 = *(const bf16x8*)(kp_ + 32);          \
    k10 = *(const bf16x8*)(kp_+1024);  k11 = *(const bf16x8*)(kp_ + 1024 + 32);   \
    k20 = *(const bf16x8*)(kp_+2048);  k21 = *(const bf16x8*)(kp_ + 2048 + 32);   \
    k30 = *(const bf16x8*)(kp_+3072);  k31 = *(const bf16x8*)(kp_ + 3072 + 32);   \
} while (0)

#define LOADV(ktv) do { \
    const unsigned short* vp_ = vbase + (ktv);                  \
    v00 = *(const bf16x8*)(vp_);             v01 = *(const bf16x8*)(vp_ + 16*NK_);      \
    v02 = *(const bf16x8*)(vp_ + 32*NK_);    v03 = *(const bf16x8*)(vp_ + 48*NK_);      \
    v10 = *(const bf16x8*)(vp_ + 32);        v11 = *(const bf16x8*)(vp_ + 16*NK_ + 32); \
    v12 = *(const bf16x8*)(vp_ + 32*NK_+32); v13 = *(const bf16x8*)(vp_ + 48*NK_ + 32); \
} while (0)

    // ---- prologue (FIFO: stage0, bits0, K0, V0) ----
    stage(0, 0);
    unsigned long long bcur = brow[0];
    LOADK(0);
    LOADV(0);
    __builtin_amdgcn_sched_barrier(0);

#pragma unroll 1
    for (int i = 0; i < 32; ++i) {
        const int kt  = i * 64;
        const int p   = i & 1;
        const int ktn = (kt + 64 < NK_) ? kt + 64 : kt;

        // ---- QK MFMA (auto-wait for K regs drains stage(i), bits(i)) ----
        f32x4 sa0 = zero4, sa1 = zero4, sa2 = zero4, sa3 = zero4;
        __builtin_amdgcn_s_setprio(1);
        sa0 = MFMA16(k00, qf0, sa0); sa0 = MFMA16(k01, qf1, sa0);
        sa1 = MFMA16(k10, qf0, sa1); sa1 = MFMA16(k11, qf1, sa1);
        sa2 = MFMA16(k20, qf0, sa2); sa2 = MFMA16(k21, qf1, sa2);
        sa3 = MFMA16(k30, qf0, sa3); sa3 = MFMA16(k31, qf1, sa3);
        __builtin_amdgcn_s_setprio(0);
        __builtin_amdgcn_sched_barrier(0);

        // ---- issue next-iter prefetches (FIFO: stage, bits, K) ----
        stage(p ^ 1, ktn);
        const unsigned long long bnxt = brow[ktn >> 6];
        LOADK(ktn);
        __builtin_amdgcn_sched_barrier(0);

        // ---- W fragments from swizzled LDS (stage(i) already drained) ----
        const float* wb = &Wlds[p][wv][0];
        float4 wfr[4];
#pragma unroll
        for (int t = 0; t < 4; ++t)
            wfr[t] = *(const float4*)(wb + r*64 + ((((4*t + g) ^ (r & 7)) << 2)));

        // ---- logits = maskbit ? -1e30 : s * w ----
        float lg[16];
        const f32x4 sav[4] = {sa0, sa1, sa2, sa3};
#pragma unroll
        for (int t = 0; t < 4; ++t) {
            const unsigned int half = (t & 2) ? (unsigned int)(bcur >> 32)
                                              : (unsigned int)bcur;
            const float wv4[4] = {wfr[t].x, wfr[t].y, wfr[t].z, wfr[t].w};
#pragma unroll
            for (int j = 0; j < 4; ++j) {
                const unsigned int bit = (half >> (16*(t & 1) + 4*g + j)) & 1u;
                lg[4*t+j] = bit ? -1e30f : sav[t][j] * wv4[j];
            }
        }

        // ---- online softmax ----
        float mx = lg[0];
#pragma unroll
        for (int i2 = 1; i2 < 16; ++i2) mx = fmaxf(mx, lg[i2]);
        mx = fmaxf(mx, __shfl_xor(mx, 16, 64));
        mx = fmaxf(mx, __shfl_xor(mx, 32, 64));
        const float mnew = fmaxf(m_run, mx);
        const float fsc  = __expf(m_run - mnew);
        m_run = mnew;
        float p16[16], rs = 0.f;
#pragma unroll
        for (int i2 = 0; i2 < 16; ++i2) { p16[i2] = __expf(lg[i2] - mnew); rs += p16[i2]; }
        rs += __shfl_xor(rs, 16, 64);
        rs += __shfl_xor(rs, 32, 64);
        l_run = l_run * fsc + rs;

        // ---- pack P -> wave-private swizzled LDS ----
#pragma unroll
        for (int t = 0; t < 4; ++t) {
            const unsigned int w0 = (unsigned int)f2bf(p16[4*t+0]) |
                                    ((unsigned int)f2bf(p16[4*t+1]) << 16);
            const unsigned int w1 = (unsigned int)f2bf(p16[4*t+2]) |
                                    ((unsigned int)f2bf(p16[4*t+3]) << 16);
            *(int2*)(pbase + roff + ((32*t + 8*g) ^ sw)) = make_int2((int)w0, (int)w1);
        }
        asm volatile("s_waitcnt lgkmcnt(0)" ::: "memory");
        __builtin_amdgcn_sched_barrier(0);
        const bf16x8 pa0 = *(const bf16x8*)(pbase + roff + ((     16*g) ^ sw));
        const bf16x8 pa1 = *(const bf16x8*)(pbase + roff + ((64 + 16*g) ^ sw));

        // ---- rescale O ----
        float fr[4];
#pragma unroll
        for (int j = 0; j < 4; ++j) fr[j] = __shfl(fsc, 4*g + j, 64);
#pragma unroll
        for (int j = 0; j < 4; ++j) {
            oa0[j] *= fr[j]; oa1[j] *= fr[j]; oa2[j] *= fr[j]; oa3[j] *= fr[j];
        }

        // ---- O += P.V (auto-wait for V regs leaves 13 prefetches in flight) ----
        __builtin_amdgcn_s_setprio(1);
        oa0 = MFMA16(pa0, v00, oa0); oa1 = MFMA16(pa0, v01, oa1);
        oa2 = MFMA16(pa0, v02, oa2); oa3 = MFMA16(pa0, v03, oa3);
        oa0 = MFMA16(pa1, v10, oa0); oa1 = MFMA16(pa1, v11, oa1);
        oa2 = MFMA16(pa1, v12, oa2); oa3 = MFMA16(pa1, v13, oa3);
        __builtin_amdgcn_s_setprio(0);
        __builtin_amdgcn_sched_barrier(0);

        // ---- issue next-iter V ----
        LOADV(ktn);
        __builtin_amdgcn_sched_barrier(0);
        bcur = bnxt;
    }
#undef LOADK
#undef LOADV

    // ---- epilogue: normalize + write (b, q, h*64+dv) fp32 ----
    const float inv = 1.0f / l_run;
    float ir[4];
#pragma unroll
    for (int j = 0; j < 4; ++j) ir[j] = __shfl(inv, 4*g + j, 64);
    const int bb = bh >> 3, h = bh & 7;
    const f32x4 oav[4] = {oa0, oa1, oa2, oa3};
#pragma unroll
    for (int nt = 0; nt < 4; ++nt)
#pragma unroll
        for (int j = 0; j < 4; ++j)
            O[((size_t)(bb*NQ_ + q0 + 4*g + j))*DM_ + h*64 + 16*nt + r] = oav[nt][j] * ir[j];
}

// ---------------------------------------------------------------------------
extern "C" void kernel_launch(void* const* d_in, const int* in_sizes, int n_in,
                              void* d_out, int out_size, void* d_ws, size_t ws_size,
                              hipStream_t stream) {
    (void)in_sizes; (void)n_in; (void)out_size; (void)ws_size;

    const float* q    = (const float*)d_in[0];
    const float* k    = (const float*)d_in[1];
    const float* v    = (const float*)d_in[2];
    const float* attw = (const float*)d_in[3];
    const unsigned char* mask = (const unsigned char*)d_in[4];
    const float* Wq = (const float*)d_in[5];
    const float* bq = (const float*)d_in[6];
    const float* Wk = (const float*)d_in[7];
    const float* bk = (const float*)d_in[8];
    const float* Wv = (const float*)d_in[9];
    const float* bv = (const float*)d_in[10];
    const float* Wo = (const float*)d_in[11];
    const float* bo = (const float*)d_in[12];
    float* out = (float*)d_out;

    // ws (shorts): q_bf[NE] k_bf[NE] vT[NE] wt[8*WL] | bits[2Mi u64] | o_ws fp32
    const long long NE = (long long)B_*H_*NQ_*DK_;        // 4Mi
    unsigned short* q_bf = (unsigned short*)d_ws;
    unsigned short* k_bf = q_bf + NE;
    unsigned short* vT   = q_bf + 2*NE;
    unsigned short* wt   = q_bf + 3*NE;
    unsigned long long* bits = (unsigned long long*)(wt + 8LL*WL_);
    const long long NB = (long long)B_*H_*NQ_*NK_/64;     // 2Mi
    float* o_ws = (float*)(bits + NB);

    const dim3 blk(256);
    wprep<<<dim3(8, 8, 4), blk, 0, stream>>>(Wq, Wk, Wv, Wo, wt);
    conv_mask<<<dim3((int)(NB/256)), blk, 0, stream>>>(mask, bits);

    const dim3 gg(128, 8);
    gemm_split<0><<<gg, blk, 0, stream>>>(q, wt + 0*WL_, wt + 1*WL_, bq, q_bf, 0.125f);
    gemm_split<0><<<gg, blk, 0, stream>>>(k, wt + 2*WL_, wt + 3*WL_, bk, k_bf, 1.0f);
    gemm_split<1><<<gg, blk, 0, stream>>>(v, wt + 4*WL_, wt + 5*WL_, bv, vT, 1.0f);

    attn_mfma<<<dim3(NQ_/64, B_*H_), blk, 0, stream>>>(q_bf, k_bf, vT, attw, bits, o_ws);

    gemm_split<2><<<gg, blk, 0, stream>>>(o_ws, wt + 6*WL_, wt + 7*WL_, bo, out, 1.0f);
}

// Round 7
// 518.353 us; speedup vs baseline: 8.7352x; 1.0475x over previous
//
#include <hip/hip_runtime.h>
#include <hip/hip_bf16.h>
#include <math.h>

#define B_   4
#define H_   8
#define NQ_  2048
#define NK_  2048
#define DM_  512
#define DK_  64
#define WL_  262144   // 512*512

typedef short  bf16x8 __attribute__((ext_vector_type(8)));
typedef float  f32x4  __attribute__((ext_vector_type(4)));

static __device__ __forceinline__ f32x4 MFMA16(bf16x8 a, bf16x8 b, f32x4 c) {
    return __builtin_amdgcn_mfma_f32_16x16x32_bf16(a, b, c, 0, 0, 0);
}
static __device__ __forceinline__ unsigned short f2bf(float f) {
    __hip_bfloat16 h = __float2bfloat16(f);
    unsigned short u; __builtin_memcpy(&u, &h, 2); return u;
}
static __device__ __forceinline__ float bf2f(unsigned short u) {
    unsigned int x = ((unsigned int)u) << 16;
    float f; __builtin_memcpy(&f, &x, 4); return f;
}
static __device__ __forceinline__ void glds16(const void* g, void* l) {
    __builtin_amdgcn_global_load_lds(
        (__attribute__((address_space(1))) const void*)g,
        (__attribute__((address_space(3))) void*)l, 16, 0, 0);
}

// ---------------------------------------------------------------------------
// mask -> bitmask, COALESCED: lane-contiguous uint4 loads (16B/lane),
// grid-stride. int32 path: 4 elems/lane -> nibble -> quad-combine (2 shfl).
// byte path: 16 elems/lane -> u16 directly.
// ---------------------------------------------------------------------------
__global__ __launch_bounds__(256) void conv_mask(const unsigned char* __restrict__ Mk,
                                                 unsigned long long* __restrict__ bits)
{
    __shared__ int s_flag;
    const int tid = threadIdx.x;
    if (tid == 0) s_flag = 0;
    __syncthreads();
    {
        bool any = false;
#pragma unroll
        for (int i = 1; i < 16; i += 4)
            if (Mk[tid*16 + i]) any = true;
        if (any) s_flag = 1;
    }
    __syncthreads();

    const long long NELEM = (long long)B_*H_*NQ_*NK_;      // 128Mi
    const long long nth   = (long long)gridDim.x * 256;
    const long long T     = (long long)blockIdx.x * 256 + tid;
    unsigned short* b16   = (unsigned short*)bits;
    const uint4*    src   = (const uint4*)Mk;

    if (s_flag) {
        // 1-byte mask: uint4 = 16 elems -> one u16 per lane
        const long long n = NELEM / 16;
        for (long long t = T; t < n; t += nth) {
            const uint4 u = src[t];
            const unsigned int w[4] = {u.x, u.y, u.z, u.w};
            unsigned int m = 0;
#pragma unroll
            for (int j = 0; j < 4; ++j)
#pragma unroll
                for (int b2 = 0; b2 < 4; ++b2)
                    if ((w[j] >> (8*b2)) & 0xffu) m |= 1u << (4*j + b2);
            b16[t] = (unsigned short)m;
        }
    } else {
        // 4-byte mask: uint4 = 4 elems -> nibble; combine quad -> u16
        const long long n = NELEM / 4;
        const int l3 = tid & 3;
        for (long long t = T; t < n; t += nth) {
            const uint4 u = src[t];
            const unsigned int nib = (u.x ? 1u : 0u) | (u.y ? 2u : 0u) |
                                     (u.z ? 4u : 0u) | (u.w ? 8u : 0u);
            unsigned int v = nib << (4*l3);
            v |= __shfl_xor(v, 1, 64);
            v |= __shfl_xor(v, 2, 64);
            if (l3 == 0) b16[t >> 2] = (unsigned short)v;
        }
    }
}

// ---------------------------------------------------------------------------
// W (512x512 fp32, [k][n]) -> WT_hi/WT_lo (bf16, [n][k]) for all 4 weights
// ---------------------------------------------------------------------------
__global__ __launch_bounds__(256) void wprep(const float* __restrict__ Wq,
                                             const float* __restrict__ Wk,
                                             const float* __restrict__ Wv,
                                             const float* __restrict__ Wo,
                                             unsigned short* __restrict__ out)
{
    __shared__ float tile[64][65];
    const int tid = threadIdx.x;
    const int k0 = blockIdx.x * 64, n0 = blockIdx.y * 64, w = blockIdx.z;
    const float* W = (w == 0) ? Wq : (w == 1) ? Wk : (w == 2) ? Wv : Wo;
    unsigned short* WTh = out + (size_t)w * 2 * WL_;
    unsigned short* WTl = WTh + WL_;

#pragma unroll
    for (int rd = 0; rd < 4; ++rd) {
        const int k = (tid >> 4) + 16*rd, c4 = (tid & 15) * 4;
        const float4 v4 = *(const float4*)(W + (size_t)(k0 + k)*DM_ + n0 + c4);
        tile[k][c4+0] = v4.x; tile[k][c4+1] = v4.y;
        tile[k][c4+2] = v4.z; tile[k][c4+3] = v4.w;
    }
    __syncthreads();
#pragma unroll
    for (int rd = 0; rd < 4; ++rd) {
        const int n = (tid >> 4) + 16*rd, kk = (tid & 15) * 4;
        unsigned short hh[4], ll[4];
#pragma unroll
        for (int j = 0; j < 4; ++j) {
            const float f = tile[kk + j][n];
            hh[j] = f2bf(f);
            ll[j] = f2bf(f - bf2f(hh[j]));
        }
        *(ushort4*)(WTh + (size_t)(n0 + n)*DM_ + k0 + kk) = make_ushort4(hh[0],hh[1],hh[2],hh[3]);
        *(ushort4*)(WTl + (size_t)(n0 + n)*DM_ + k0 + kk) = make_ushort4(ll[0],ll[1],ll[2],ll[3]);
    }
}

// ---------------------------------------------------------------------------
// Split-bf16 MFMA GEMM: C = A(fp32) @ W + bias (x oscale).
// MODE 0/1: 2-term (Ah*Wh + Ah*Wl) -> bf16 out (error ~ bf16 rounding).
// MODE 2:   3-term (+ Al*Wh)       -> fp32 out (final projection).
// MODE 0: (B,H,N,64) layout  MODE 1: (B,H,64,NK) (V^T)  MODE 2: row-major
// ---------------------------------------------------------------------------
template<int MODE>
__global__ __launch_bounds__(256) void gemm_split(
    const float* __restrict__ A,
    const unsigned short* __restrict__ WTh,
    const unsigned short* __restrict__ WTl,
    const float* __restrict__ bias,
    void* __restrict__ outv, const float oscale)
{
    __shared__ unsigned short Ah[64][64], Al[64][64], Bh[64][64], Bl[64][64];

    const int tid = threadIdx.x;
    const int w = tid >> 6, lane = tid & 63, g = lane >> 4, r = lane & 15;
    const int m0 = blockIdx.x * 64, n0 = blockIdx.y * 64;

    char* pAh = (char*)&Ah[0][0];
    char* pAl = (char*)&Al[0][0];
    char* pBh = (char*)&Bh[0][0];
    char* pBl = (char*)&Bl[0][0];

    const f32x4 z4 = {0.f, 0.f, 0.f, 0.f};
    f32x4 acc[4] = {z4, z4, z4, z4};

    for (int kt = 0; kt < DM_; kt += 64) {
#pragma unroll
        for (int rd = 0; rd < 4; ++rd) {
            const int row = (tid >> 4) + 16*rd;
            const int c4  = (tid & 15) * 4;
            const float4 a4 = *(const float4*)(A + (size_t)(m0 + row)*DM_ + kt + c4);
            const float av[4] = {a4.x, a4.y, a4.z, a4.w};
            unsigned short hh[4];
#pragma unroll
            for (int j = 0; j < 4; ++j) hh[j] = f2bf(av[j]);
            const int bo = (c4 * 2) ^ ((row & 7) << 4);
            *(ushort4*)(pAh + row*128 + bo) = make_ushort4(hh[0],hh[1],hh[2],hh[3]);
            if (MODE == 2) {
                unsigned short ll[4];
#pragma unroll
                for (int j = 0; j < 4; ++j) ll[j] = f2bf(av[j] - bf2f(hh[j]));
                *(ushort4*)(pAl + row*128 + bo) = make_ushort4(ll[0],ll[1],ll[2],ll[3]);
            }
        }
#pragma unroll
        for (int rd = 0; rd < 2; ++rd) {
            const int idx = tid + 256*rd;
            const int row = idx >> 3;
            const int cb  = (idx & 7) * 16;
            const int bo  = cb ^ ((row & 7) << 4);
            const size_t goff = (size_t)(n0 + row)*DM_ + kt + (cb >> 1);
            *(bf16x8*)(pBh + row*128 + bo) = *(const bf16x8*)(WTh + goff);
            *(bf16x8*)(pBl + row*128 + bo) = *(const bf16x8*)(WTl + goff);
        }
        __syncthreads();

        const int swr = (r & 7) << 4;
#pragma unroll
        for (int ks = 0; ks < 2; ++ks) {
            const int xo = (64*ks + 16*g) ^ swr;
            const bf16x8 xh = *(const bf16x8*)(pAh + (16*w + r)*128 + xo);
#pragma unroll
            for (int nt = 0; nt < 4; ++nt) {
                const bf16x8 bh = *(const bf16x8*)(pBh + (16*nt + r)*128 + xo);
                const bf16x8 bl = *(const bf16x8*)(pBl + (16*nt + r)*128 + xo);
                if (MODE == 1) {
                    acc[nt] = MFMA16(xh, bh, acc[nt]);
                    acc[nt] = MFMA16(xh, bl, acc[nt]);
                } else if (MODE == 0) {
                    acc[nt] = MFMA16(bh, xh, acc[nt]);
                    acc[nt] = MFMA16(bl, xh, acc[nt]);
                } else {
                    const bf16x8 xl = *(const bf16x8*)(pAl + (16*w + r)*128 + xo);
                    acc[nt] = MFMA16(bh, xh, acc[nt]);
                    acc[nt] = MFMA16(bh, xl, acc[nt]);
                    acc[nt] = MFMA16(bl, xh, acc[nt]);
                }
            }
        }
        __syncthreads();
    }

    if (MODE == 0) {
        const int m = m0 + 16*w + r;
        const int b = m >> 11, q = m & 2047, h = blockIdx.y;
        unsigned short* dst = (unsigned short*)outv + (((size_t)(b*H_ + h))*NQ_ + q)*DK_;
#pragma unroll
        for (int nt = 0; nt < 4; ++nt) {
            unsigned short u[4];
#pragma unroll
            for (int j = 0; j < 4; ++j)
                u[j] = f2bf((acc[nt][j] + bias[n0 + 16*nt + 4*g + j]) * oscale);
            *(ushort4*)(dst + 16*nt + 4*g) = make_ushort4(u[0],u[1],u[2],u[3]);
        }
    } else if (MODE == 1) {
        const int b = m0 >> 11, h = blockIdx.y;
        const int key = (m0 & 2047) + 16*w + 4*g;
#pragma unroll
        for (int nt = 0; nt < 4; ++nt) {
            const int dv = 16*nt + r;
            const float bv = bias[n0 + dv];
            unsigned short u[4];
#pragma unroll
            for (int j = 0; j < 4; ++j) u[j] = f2bf(acc[nt][j] + bv);
            *(ushort4*)((unsigned short*)outv +
                        (((size_t)(b*H_ + h))*DK_ + dv)*NK_ + key) = make_ushort4(u[0],u[1],u[2],u[3]);
        }
    } else {
        const int m = m0 + 16*w + r;
        float* dst = (float*)outv + (size_t)m*DM_ + n0;
#pragma unroll
        for (int nt = 0; nt < 4; ++nt) {
            float4 o4;
            o4.x = acc[nt][0] + bias[n0 + 16*nt + 4*g + 0];
            o4.y = acc[nt][1] + bias[n0 + 16*nt + 4*g + 1];
            o4.z = acc[nt][2] + bias[n0 + 16*nt + 4*g + 2];
            o4.w = acc[nt][3] + bias[n0 + 16*nt + 4*g + 3];
            *(float4*)(dst + 16*nt + 4*g) = o4;
        }
    }
}

// ---------------------------------------------------------------------------
// MFMA flash attention. 4 waves = 4 q-subblocks of 16 rows; K-step 64.
// All fragments in NAMED registers. Pipeline per iter i (FIFO pinned):
//   QK(i) -> issue stage(i+1),bits(i+1),K(i+1) -> W-frags from LDS, softmax,
//   P-pack -> PV(i) -> issue V(i+1).
// ---------------------------------------------------------------------------
__global__ __launch_bounds__(256) void attn_mfma(
    const unsigned short* __restrict__ Qb,
    const unsigned short* __restrict__ Kb,
    const unsigned short* __restrict__ Vt,
    const float* __restrict__ Wt,
    const unsigned long long* __restrict__ Mb,
    float* __restrict__ O)
{
    __shared__ float Wlds[2][4][1024];   // [buf][wave][16 rows x 64 cols] swizzled
    __shared__ short Pl[4][1024];        // P bounce, 2KB/wave

    const int tid  = threadIdx.x;
    const int wv   = tid >> 6, lane = tid & 63;
    const int g    = lane >> 4, r = lane & 15;
    const int q0   = blockIdx.x * 64 + wv * 16;
    const int bh   = blockIdx.y;

    const size_t kvBase = (size_t)bh * NK_ * DK_;
    const unsigned short* qp = Qb + kvBase + (size_t)(q0 + r)*DK_ + 8*g;
    const bf16x8 qf0 = *(const bf16x8*)qp;
    const bf16x8 qf1 = *(const bf16x8*)(qp + 32);

    const float* wrow_base = Wt + ((size_t)bh*NQ_ + q0)*NK_;
    const unsigned long long* brow = Mb + ((size_t)bh*NQ_ + q0 + r)*(NK_/64);
    const unsigned short* kbase = Kb + kvBase + (size_t)r*DK_ + 8*g;
    const unsigned short* vbase = Vt + kvBase + (size_t)r*NK_ + 8*g;

    const f32x4 zero4 = {0.f, 0.f, 0.f, 0.f};
    f32x4 oa0 = zero4, oa1 = zero4, oa2 = zero4, oa3 = zero4;
    float m_run = -1e30f, l_run = 0.f;

    char* pbase = (char*)&Pl[wv][0];
    const int roff = r * 128;
    const int sw   = (r & 7) << 4;

    auto stage = [&](int buf, int kt) {
        float* base = &Wlds[buf][wv][0];
#pragma unroll
        for (int c = 0; c < 4; ++c) {
            const int row = c*4 + (lane >> 4);
            const int blk = (lane & 15) ^ (row & 7);
            glds16(wrow_base + (size_t)row*NK_ + kt + blk*4, base + c*256 + lane*4);
        }
    };

    bf16x8 k00,k01,k10,k11,k20,k21,k30,k31;
    bf16x8 v00,v01,v02,v03, v10,v11,v12,v13;

#define LOADK(ktv) do { \
    const unsigned short* kp_ = kbase + (size_t)(ktv)*DK_;      \
    k00 = *(const bf16x8*)kp_;         k01 = *(const bf16x8*)(kp_ + 32);          \
    k10 = *(const bf16x8*)(kp_+1024);  k11 = *(const bf16x8*)(kp_ + 1024 + 32);   \
    k20 = *(const bf16x8*)(kp_+2048);  k21 = *(const bf16x8*)(kp_ + 2048 + 32);   \
    k30 = *(const bf16x8*)(kp_+3072);  k31 = *(const bf16x8*)(kp_ + 3072 + 32);   \
} while (0)

#define LOADV(ktv) do { \
    const unsigned short* vp_ = vbase + (ktv);                  \
    v00 = *(const bf16x8*)(vp_);             v01 = *(const bf16x8*)(vp_ + 16*NK_);      \
    v02 = *(const bf16x8*)(vp_ + 32*NK_);    v03 = *(const bf16x8*)(vp_ + 48*NK_);      \
    v10 = *(const bf16x8*)(vp_ + 32);        v11 = *(const bf16x8*)(vp_ + 16*NK_ + 32); \
    v12 = *(const bf16x8*)(vp_ + 32*NK_+32); v13 = *(const bf16x8*)(vp_ + 48*NK_ + 32); \
} while (0)

    // ---- prologue (FIFO: stage0, bits0, K0, V0) ----
    stage(0, 0);
    unsigned long long bcur = brow[0];
    LOADK(0);
    LOADV(0);
    __builtin_amdgcn_sched_barrier(0);

#pragma unroll 1
    for (int i = 0; i < 32; ++i) {
        const int kt  = i * 64;
        const int p   = i & 1;
        const int ktn = (kt + 64 < NK_) ? kt + 64 : kt;

        // ---- QK MFMA ----
        f32x4 sa0 = zero4, sa1 = zero4, sa2 = zero4, sa3 = zero4;
        __builtin_amdgcn_s_setprio(1);
        sa0 = MFMA16(k00, qf0, sa0); sa0 = MFMA16(k01, qf1, sa0);
        sa1 = MFMA16(k10, qf0, sa1); sa1 = MFMA16(k11, qf1, sa1);
        sa2 = MFMA16(k20, qf0, sa2); sa2 = MFMA16(k21, qf1, sa2);
        sa3 = MFMA16(k30, qf0, sa3); sa3 = MFMA16(k31, qf1, sa3);
        __builtin_amdgcn_s_setprio(0);
        __builtin_amdgcn_sched_barrier(0);

        // ---- issue next-iter prefetches (FIFO: stage, bits, K) ----
        stage(p ^ 1, ktn);
        const unsigned long long bnxt = brow[ktn >> 6];
        LOADK(ktn);
        __builtin_amdgcn_sched_barrier(0);

        // ---- W fragments from swizzled LDS ----
        const float* wb = &Wlds[p][wv][0];
        float4 wfr[4];
#pragma unroll
        for (int t = 0; t < 4; ++t)
            wfr[t] = *(const float4*)(wb + r*64 + ((((4*t + g) ^ (r & 7)) << 2)));

        // ---- logits = maskbit ? -1e30 : s * w ----
        float lg[16];
        const f32x4 sav[4] = {sa0, sa1, sa2, sa3};
#pragma unroll
        for (int t = 0; t < 4; ++t) {
            const unsigned int half = (t & 2) ? (unsigned int)(bcur >> 32)
                                              : (unsigned int)bcur;
            const float wv4[4] = {wfr[t].x, wfr[t].y, wfr[t].z, wfr[t].w};
#pragma unroll
            for (int j = 0; j < 4; ++j) {
                const unsigned int bit = (half >> (16*(t & 1) + 4*g + j)) & 1u;
                lg[4*t+j] = bit ? -1e30f : sav[t][j] * wv4[j];
            }
        }

        // ---- online softmax ----
        float mx = lg[0];
#pragma unroll
        for (int i2 = 1; i2 < 16; ++i2) mx = fmaxf(mx, lg[i2]);
        mx = fmaxf(mx, __shfl_xor(mx, 16, 64));
        mx = fmaxf(mx, __shfl_xor(mx, 32, 64));
        const float mnew = fmaxf(m_run, mx);
        const float fsc  = __expf(m_run - mnew);
        m_run = mnew;
        float p16[16], rs = 0.f;
#pragma unroll
        for (int i2 = 0; i2 < 16; ++i2) { p16[i2] = __expf(lg[i2] - mnew); rs += p16[i2]; }
        rs += __shfl_xor(rs, 16, 64);
        rs += __shfl_xor(rs, 32, 64);
        l_run = l_run * fsc + rs;

        // ---- pack P -> wave-private swizzled LDS ----
#pragma unroll
        for (int t = 0; t < 4; ++t) {
            const unsigned int w0 = (unsigned int)f2bf(p16[4*t+0]) |
                                    ((unsigned int)f2bf(p16[4*t+1]) << 16);
            const unsigned int w1 = (unsigned int)f2bf(p16[4*t+2]) |
                                    ((unsigned int)f2bf(p16[4*t+3]) << 16);
            *(int2*)(pbase + roff + ((32*t + 8*g) ^ sw)) = make_int2((int)w0, (int)w1);
        }
        asm volatile("s_waitcnt lgkmcnt(0)" ::: "memory");
        __builtin_amdgcn_sched_barrier(0);
        const bf16x8 pa0 = *(const bf16x8*)(pbase + roff + ((     16*g) ^ sw));
        const bf16x8 pa1 = *(const bf16x8*)(pbase + roff + ((64 + 16*g) ^ sw));

        // ---- rescale O ----
        float fr[4];
#pragma unroll
        for (int j = 0; j < 4; ++j) fr[j] = __shfl(fsc, 4*g + j, 64);
#pragma unroll
        for (int j = 0; j < 4; ++j) {
            oa0[j] *= fr[j]; oa1[j] *= fr[j]; oa2[j] *= fr[j]; oa3[j] *= fr[j];
        }

        // ---- O += P.V ----
        __builtin_amdgcn_s_setprio(1);
        oa0 = MFMA16(pa0, v00, oa0); oa1 = MFMA16(pa0, v01, oa1);
        oa2 = MFMA16(pa0, v02, oa2); oa3 = MFMA16(pa0, v03, oa3);
        oa0 = MFMA16(pa1, v10, oa0); oa1 = MFMA16(pa1, v11, oa1);
        oa2 = MFMA16(pa1, v12, oa2); oa3 = MFMA16(pa1, v13, oa3);
        __builtin_amdgcn_s_setprio(0);
        __builtin_amdgcn_sched_barrier(0);

        // ---- issue next-iter V ----
        LOADV(ktn);
        __builtin_amdgcn_sched_barrier(0);
        bcur = bnxt;
    }
#undef LOADK
#undef LOADV

    // ---- epilogue: normalize + write (b, q, h*64+dv) fp32 ----
    const float inv = 1.0f / l_run;
    float ir[4];
#pragma unroll
    for (int j = 0; j < 4; ++j) ir[j] = __shfl(inv, 4*g + j, 64);
    const int bb = bh >> 3, h = bh & 7;
    const f32x4 oav[4] = {oa0, oa1, oa2, oa3};
#pragma unroll
    for (int nt = 0; nt < 4; ++nt)
#pragma unroll
        for (int j = 0; j < 4; ++j)
            O[((size_t)(bb*NQ_ + q0 + 4*g + j))*DM_ + h*64 + 16*nt + r] = oav[nt][j] * ir[j];
}

// ---------------------------------------------------------------------------
extern "C" void kernel_launch(void* const* d_in, const int* in_sizes, int n_in,
                              void* d_out, int out_size, void* d_ws, size_t ws_size,
                              hipStream_t stream) {
    (void)in_sizes; (void)n_in; (void)out_size; (void)ws_size;

    const float* q    = (const float*)d_in[0];
    const float* k    = (const float*)d_in[1];
    const float* v    = (const float*)d_in[2];
    const float* attw = (const float*)d_in[3];
    const unsigned char* mask = (const unsigned char*)d_in[4];
    const float* Wq = (const float*)d_in[5];
    const float* bq = (const float*)d_in[6];
    const float* Wk = (const float*)d_in[7];
    const float* bk = (const float*)d_in[8];
    const float* Wv = (const float*)d_in[9];
    const float* bv = (const float*)d_in[10];
    const float* Wo = (const float*)d_in[11];
    const float* bo = (const float*)d_in[12];
    float* out = (float*)d_out;

    // ws (shorts): q_bf[NE] k_bf[NE] vT[NE] wt[8*WL] | bits[2Mi u64] | o_ws fp32
    const long long NE = (long long)B_*H_*NQ_*DK_;        // 4Mi
    unsigned short* q_bf = (unsigned short*)d_ws;
    unsigned short* k_bf = q_bf + NE;
    unsigned short* vT   = q_bf + 2*NE;
    unsigned short* wt   = q_bf + 3*NE;
    unsigned long long* bits = (unsigned long long*)(wt + 8LL*WL_);
    const long long NB = (long long)B_*H_*NQ_*NK_/64;     // 2Mi
    float* o_ws = (float*)(bits + NB);

    const dim3 blk(256);
    wprep<<<dim3(8, 8, 4), blk, 0, stream>>>(Wq, Wk, Wv, Wo, wt);
    conv_mask<<<dim3(2048), blk, 0, stream>>>(mask, bits);

    const dim3 gg(128, 8);
    gemm_split<0><<<gg, blk, 0, stream>>>(q, wt + 0*WL_, wt + 1*WL_, bq, q_bf, 0.125f);
    gemm_split<0><<<gg, blk, 0, stream>>>(k, wt + 2*WL_, wt + 3*WL_, bk, k_bf, 1.0f);
    gemm_split<1><<<gg, blk, 0, stream>>>(v, wt + 4*WL_, wt + 5*WL_, bv, vT, 1.0f);

    attn_mfma<<<dim3(NQ_/64, B_*H_), blk, 0, stream>>>(q_bf, k_bf, vT, attw, bits, o_ws);

    gemm_split<2><<<gg, blk, 0, stream>>>(o_ws, wt + 6*WL_, wt + 7*WL_, bo, out, 1.0f);
}

// Round 8
// 517.248 us; speedup vs baseline: 8.7539x; 1.0021x over previous
//
#include <hip/hip_runtime.h>
#include <hip/hip_bf16.h>
#include <math.h>

#define B_   4
#define H_   8
#define NQ_  2048
#define NK_  2048
#define DM_  512
#define DK_  64
#define WL_  262144   // 512*512

typedef short  bf16x8 __attribute__((ext_vector_type(8)));
typedef float  f32x4  __attribute__((ext_vector_type(4)));

static __device__ __forceinline__ f32x4 MFMA16(bf16x8 a, bf16x8 b, f32x4 c) {
    return __builtin_amdgcn_mfma_f32_16x16x32_bf16(a, b, c, 0, 0, 0);
}
static __device__ __forceinline__ unsigned short f2bf(float f) {
    __hip_bfloat16 h = __float2bfloat16(f);
    unsigned short u; __builtin_memcpy(&u, &h, 2); return u;
}
static __device__ __forceinline__ float bf2f(unsigned short u) {
    unsigned int x = ((unsigned int)u) << 16;
    float f; __builtin_memcpy(&f, &x, 4); return f;
}
static __device__ __forceinline__ void glds16(const void* g, void* l) {
    __builtin_amdgcn_global_load_lds(
        (__attribute__((address_space(1))) const void*)g,
        (__attribute__((address_space(3))) void*)l, 16, 0, 0);
}

// ---------------------------------------------------------------------------
// mask -> bitmask, coalesced (lane-contiguous uint4 loads, grid-stride)
// ---------------------------------------------------------------------------
__global__ __launch_bounds__(256) void conv_mask(const unsigned char* __restrict__ Mk,
                                                 unsigned long long* __restrict__ bits)
{
    __shared__ int s_flag;
    const int tid = threadIdx.x;
    if (tid == 0) s_flag = 0;
    __syncthreads();
    {
        bool any = false;
#pragma unroll
        for (int i = 1; i < 16; i += 4)
            if (Mk[tid*16 + i]) any = true;
        if (any) s_flag = 1;
    }
    __syncthreads();

    const long long NELEM = (long long)B_*H_*NQ_*NK_;      // 128Mi
    const long long nth   = (long long)gridDim.x * 256;
    const long long T     = (long long)blockIdx.x * 256 + tid;
    unsigned short* b16   = (unsigned short*)bits;
    const uint4*    src   = (const uint4*)Mk;

    if (s_flag) {
        const long long n = NELEM / 16;
        for (long long t = T; t < n; t += nth) {
            const uint4 u = src[t];
            const unsigned int w[4] = {u.x, u.y, u.z, u.w};
            unsigned int m = 0;
#pragma unroll
            for (int j = 0; j < 4; ++j)
#pragma unroll
                for (int b2 = 0; b2 < 4; ++b2)
                    if ((w[j] >> (8*b2)) & 0xffu) m |= 1u << (4*j + b2);
            b16[t] = (unsigned short)m;
        }
    } else {
        const long long n = NELEM / 4;
        const int l3 = tid & 3;
        for (long long t = T; t < n; t += nth) {
            const uint4 u = src[t];
            const unsigned int nib = (u.x ? 1u : 0u) | (u.y ? 2u : 0u) |
                                     (u.z ? 4u : 0u) | (u.w ? 8u : 0u);
            unsigned int v = nib << (4*l3);
            v |= __shfl_xor(v, 1, 64);
            v |= __shfl_xor(v, 2, 64);
            if (l3 == 0) b16[t >> 2] = (unsigned short)v;
        }
    }
}

// ---------------------------------------------------------------------------
// W (512x512 fp32, [k][n]) -> WT_hi/WT_lo (bf16, [n][k]) for all 4 weights
// ---------------------------------------------------------------------------
__global__ __launch_bounds__(256) void wprep(const float* __restrict__ Wq,
                                             const float* __restrict__ Wk,
                                             const float* __restrict__ Wv,
                                             const float* __restrict__ Wo,
                                             unsigned short* __restrict__ out)
{
    __shared__ float tile[64][65];
    const int tid = threadIdx.x;
    const int k0 = blockIdx.x * 64, n0 = blockIdx.y * 64, w = blockIdx.z;
    const float* W = (w == 0) ? Wq : (w == 1) ? Wk : (w == 2) ? Wv : Wo;
    unsigned short* WTh = out + (size_t)w * 2 * WL_;
    unsigned short* WTl = WTh + WL_;

#pragma unroll
    for (int rd = 0; rd < 4; ++rd) {
        const int k = (tid >> 4) + 16*rd, c4 = (tid & 15) * 4;
        const float4 v4 = *(const float4*)(W + (size_t)(k0 + k)*DM_ + n0 + c4);
        tile[k][c4+0] = v4.x; tile[k][c4+1] = v4.y;
        tile[k][c4+2] = v4.z; tile[k][c4+3] = v4.w;
    }
    __syncthreads();
#pragma unroll
    for (int rd = 0; rd < 4; ++rd) {
        const int n = (tid >> 4) + 16*rd, kk = (tid & 15) * 4;
        unsigned short hh[4], ll[4];
#pragma unroll
        for (int j = 0; j < 4; ++j) {
            const float f = tile[kk + j][n];
            hh[j] = f2bf(f);
            ll[j] = f2bf(f - bf2f(hh[j]));
        }
        *(ushort4*)(WTh + (size_t)(n0 + n)*DM_ + k0 + kk) = make_ushort4(hh[0],hh[1],hh[2],hh[3]);
        *(ushort4*)(WTl + (size_t)(n0 + n)*DM_ + k0 + kk) = make_ushort4(ll[0],ll[1],ll[2],ll[3]);
    }
}

// ---------------------------------------------------------------------------
// Split-bf16 MFMA GEMM: C = A(fp32) @ W + bias (x oscale).
// MODE 0/1: 2-term (Ah*Wh + Ah*Wl) -> bf16 out.  MODE 2: 3-term -> fp32 out.
// ---------------------------------------------------------------------------
template<int MODE>
__global__ __launch_bounds__(256) void gemm_split(
    const float* __restrict__ A,
    const unsigned short* __restrict__ WTh,
    const unsigned short* __restrict__ WTl,
    const float* __restrict__ bias,
    void* __restrict__ outv, const float oscale)
{
    __shared__ unsigned short Ah[64][64], Al[64][64], Bh[64][64], Bl[64][64];

    const int tid = threadIdx.x;
    const int w = tid >> 6, lane = tid & 63, g = lane >> 4, r = lane & 15;
    const int m0 = blockIdx.x * 64, n0 = blockIdx.y * 64;

    char* pAh = (char*)&Ah[0][0];
    char* pAl = (char*)&Al[0][0];
    char* pBh = (char*)&Bh[0][0];
    char* pBl = (char*)&Bl[0][0];

    const f32x4 z4 = {0.f, 0.f, 0.f, 0.f};
    f32x4 acc[4] = {z4, z4, z4, z4};

    for (int kt = 0; kt < DM_; kt += 64) {
#pragma unroll
        for (int rd = 0; rd < 4; ++rd) {
            const int row = (tid >> 4) + 16*rd;
            const int c4  = (tid & 15) * 4;
            const float4 a4 = *(const float4*)(A + (size_t)(m0 + row)*DM_ + kt + c4);
            const float av[4] = {a4.x, a4.y, a4.z, a4.w};
            unsigned short hh[4];
#pragma unroll
            for (int j = 0; j < 4; ++j) hh[j] = f2bf(av[j]);
            const int bo = (c4 * 2) ^ ((row & 7) << 4);
            *(ushort4*)(pAh + row*128 + bo) = make_ushort4(hh[0],hh[1],hh[2],hh[3]);
            if (MODE == 2) {
                unsigned short ll[4];
#pragma unroll
                for (int j = 0; j < 4; ++j) ll[j] = f2bf(av[j] - bf2f(hh[j]));
                *(ushort4*)(pAl + row*128 + bo) = make_ushort4(ll[0],ll[1],ll[2],ll[3]);
            }
        }
#pragma unroll
        for (int rd = 0; rd < 2; ++rd) {
            const int idx = tid + 256*rd;
            const int row = idx >> 3;
            const int cb  = (idx & 7) * 16;
            const int bo  = cb ^ ((row & 7) << 4);
            const size_t goff = (size_t)(n0 + row)*DM_ + kt + (cb >> 1);
            *(bf16x8*)(pBh + row*128 + bo) = *(const bf16x8*)(WTh + goff);
            *(bf16x8*)(pBl + row*128 + bo) = *(const bf16x8*)(WTl + goff);
        }
        __syncthreads();

        const int swr = (r & 7) << 4;
#pragma unroll
        for (int ks = 0; ks < 2; ++ks) {
            const int xo = (64*ks + 16*g) ^ swr;
            const bf16x8 xh = *(const bf16x8*)(pAh + (16*w + r)*128 + xo);
#pragma unroll
            for (int nt = 0; nt < 4; ++nt) {
                const bf16x8 bh = *(const bf16x8*)(pBh + (16*nt + r)*128 + xo);
                const bf16x8 bl = *(const bf16x8*)(pBl + (16*nt + r)*128 + xo);
                if (MODE == 1) {
                    acc[nt] = MFMA16(xh, bh, acc[nt]);
                    acc[nt] = MFMA16(xh, bl, acc[nt]);
                } else if (MODE == 0) {
                    acc[nt] = MFMA16(bh, xh, acc[nt]);
                    acc[nt] = MFMA16(bl, xh, acc[nt]);
                } else {
                    const bf16x8 xl = *(const bf16x8*)(pAl + (16*w + r)*128 + xo);
                    acc[nt] = MFMA16(bh, xh, acc[nt]);
                    acc[nt] = MFMA16(bh, xl, acc[nt]);
                    acc[nt] = MFMA16(bl, xh, acc[nt]);
                }
            }
        }
        __syncthreads();
    }

    if (MODE == 0) {
        const int m = m0 + 16*w + r;
        const int b = m >> 11, q = m & 2047, h = blockIdx.y;
        unsigned short* dst = (unsigned short*)outv + (((size_t)(b*H_ + h))*NQ_ + q)*DK_;
#pragma unroll
        for (int nt = 0; nt < 4; ++nt) {
            unsigned short u[4];
#pragma unroll
            for (int j = 0; j < 4; ++j)
                u[j] = f2bf((acc[nt][j] + bias[n0 + 16*nt + 4*g + j]) * oscale);
            *(ushort4*)(dst + 16*nt + 4*g) = make_ushort4(u[0],u[1],u[2],u[3]);
        }
    } else if (MODE == 1) {
        const int b = m0 >> 11, h = blockIdx.y;
        const int key = (m0 & 2047) + 16*w + 4*g;
#pragma unroll
        for (int nt = 0; nt < 4; ++nt) {
            const int dv = 16*nt + r;
            const float bv = bias[n0 + dv];
            unsigned short u[4];
#pragma unroll
            for (int j = 0; j < 4; ++j) u[j] = f2bf(acc[nt][j] + bv);
            *(ushort4*)((unsigned short*)outv +
                        (((size_t)(b*H_ + h))*DK_ + dv)*NK_ + key) = make_ushort4(u[0],u[1],u[2],u[3]);
        }
    } else {
        const int m = m0 + 16*w + r;
        float* dst = (float*)outv + (size_t)m*DM_ + n0;
#pragma unroll
        for (int nt = 0; nt < 4; ++nt) {
            float4 o4;
            o4.x = acc[nt][0] + bias[n0 + 16*nt + 4*g + 0];
            o4.y = acc[nt][1] + bias[n0 + 16*nt + 4*g + 1];
            o4.z = acc[nt][2] + bias[n0 + 16*nt + 4*g + 2];
            o4.w = acc[nt][3] + bias[n0 + 16*nt + 4*g + 3];
            *(float4*)(dst + 16*nt + 4*g) = o4;
        }
    }
}

// ---------------------------------------------------------------------------
// MFMA flash attention. 4 waves = 4 q-subblocks of 16 rows; K-step 64.
// KEY ORDERING (this round): the Wlds ds_read (which may force a compiler
// vmcnt(0) drain due to the glds->ds_read dependence) happens BEFORE the
// next-iter prefetch issue, so a forced drain only hits V(i) (1 iter old,
// L2) instead of the fresh stage/K prefetches. K single-buffered.
// ---------------------------------------------------------------------------
__global__ __launch_bounds__(256) void attn_mfma(
    const unsigned short* __restrict__ Qb,
    const unsigned short* __restrict__ Kb,
    const unsigned short* __restrict__ Vt,
    const float* __restrict__ Wt,
    const unsigned long long* __restrict__ Mb,
    float* __restrict__ O)
{
    __shared__ float Wlds[2][4][1024];   // [buf][wave][16 rows x 64 cols] swizzled
    __shared__ short Pl[4][1024];        // P bounce, 2KB/wave

    const int tid  = threadIdx.x;
    const int wv   = tid >> 6, lane = tid & 63;
    const int g    = lane >> 4, r = lane & 15;
    const int q0   = blockIdx.x * 64 + wv * 16;
    const int bh   = blockIdx.y;

    const size_t kvBase = (size_t)bh * NK_ * DK_;
    const unsigned short* qp = Qb + kvBase + (size_t)(q0 + r)*DK_ + 8*g;
    const bf16x8 qf0 = *(const bf16x8*)qp;
    const bf16x8 qf1 = *(const bf16x8*)(qp + 32);

    const float* wrow_base = Wt + ((size_t)bh*NQ_ + q0)*NK_;
    const unsigned long long* brow = Mb + ((size_t)bh*NQ_ + q0 + r)*(NK_/64);
    const unsigned short* kbase = Kb + kvBase + (size_t)r*DK_ + 8*g;
    const unsigned short* vbase = Vt + kvBase + (size_t)r*NK_ + 8*g;

    const f32x4 zero4 = {0.f, 0.f, 0.f, 0.f};
    f32x4 oa0 = zero4, oa1 = zero4, oa2 = zero4, oa3 = zero4;
    float m_run = -1e30f, l_run = 0.f;

    char* pbase = (char*)&Pl[wv][0];
    const int roff = r * 128;
    const int sw   = (r & 7) << 4;

    auto stage = [&](int buf, int kt) {
        float* base = &Wlds[buf][wv][0];
#pragma unroll
        for (int c = 0; c < 4; ++c) {
            const int row = c*4 + (lane >> 4);
            const int blk = (lane & 15) ^ (row & 7);
            glds16(wrow_base + (size_t)row*NK_ + kt + blk*4, base + c*256 + lane*4);
        }
    };

    bf16x8 k00,k01,k10,k11,k20,k21,k30,k31;           // single-buffered K
    bf16x8 v00,v01,v02,v03, v10,v11,v12,v13;          // single-buffered V

#define LOADK(ktv) do { \
    const unsigned short* kp_ = kbase + (size_t)(ktv)*DK_;      \
    k00 = *(const bf16x8*)kp_;         k01 = *(const bf16x8*)(kp_ + 32);          \
    k10 = *(const bf16x8*)(kp_+1024);  k11 = *(const bf16x8*)(kp_ + 1024 + 32);   \
    k20 = *(const bf16x8*)(kp_+2048);  k21 = *(const bf16x8*)(kp_ + 2048 + 32);   \
    k30 = *(const bf16x8*)(kp_+3072);  k31 = *(const bf16x8*)(kp_ + 3072 + 32);   \
} while (0)

#define LOADV(ktv) do { \
    const unsigned short* vp_ = vbase + (ktv);                  \
    v00 = *(const bf16x8*)(vp_);             v01 = *(const bf16x8*)(vp_ + 16*NK_);      \
    v02 = *(const bf16x8*)(vp_ + 32*NK_);    v03 = *(const bf16x8*)(vp_ + 48*NK_);      \
    v10 = *(const bf16x8*)(vp_ + 32);        v11 = *(const bf16x8*)(vp_ + 16*NK_ + 32); \
    v12 = *(const bf16x8*)(vp_ + 32*NK_+32); v13 = *(const bf16x8*)(vp_ + 48*NK_ + 32); \
} while (0)

    // ---- prologue ----
    stage(0, 0);
    unsigned long long bcur = brow[0];
    LOADK(0);
    LOADV(0);
    __builtin_amdgcn_sched_barrier(0);

#pragma unroll 1
    for (int i = 0; i < 32; ++i) {
        const int kt  = i * 64;
        const int p   = i & 1;
        const int ktn = (kt + 64 < NK_) ? kt + 64 : kt;

        // ---- QK MFMA (counted K-wait FIFO-drains stage(i) for free) ----
        f32x4 sa0 = zero4, sa1 = zero4, sa2 = zero4, sa3 = zero4;
        __builtin_amdgcn_s_setprio(1);
        sa0 = MFMA16(k00, qf0, sa0); sa0 = MFMA16(k01, qf1, sa0);
        sa1 = MFMA16(k10, qf0, sa1); sa1 = MFMA16(k11, qf1, sa1);
        sa2 = MFMA16(k20, qf0, sa2); sa2 = MFMA16(k21, qf1, sa2);
        sa3 = MFMA16(k30, qf0, sa3); sa3 = MFMA16(k31, qf1, sa3);
        __builtin_amdgcn_s_setprio(0);
        __builtin_amdgcn_sched_barrier(0);

        // ---- W fragments from swizzled LDS (BEFORE any new prefetch issue:
        //      a forced vmcnt(0) here drains only the iter-old V(i)) ----
        const float* wb = &Wlds[p][wv][0];
        float4 wfr[4];
#pragma unroll
        for (int t = 0; t < 4; ++t)
            wfr[t] = *(const float4*)(wb + r*64 + ((((4*t + g) ^ (r & 7)) << 2)));

        // ---- logits = maskbit ? -1e30 : s * w ----
        float lg[16];
        const f32x4 sav[4] = {sa0, sa1, sa2, sa3};
#pragma unroll
        for (int t = 0; t < 4; ++t) {
            const unsigned int half = (t & 2) ? (unsigned int)(bcur >> 32)
                                              : (unsigned int)bcur;
            const float wv4[4] = {wfr[t].x, wfr[t].y, wfr[t].z, wfr[t].w};
#pragma unroll
            for (int j = 0; j < 4; ++j) {
                const unsigned int bit = (half >> (16*(t & 1) + 4*g + j)) & 1u;
                lg[4*t+j] = bit ? -1e30f : sav[t][j] * wv4[j];
            }
        }

        // ---- online softmax ----
        float mx = lg[0];
#pragma unroll
        for (int i2 = 1; i2 < 16; ++i2) mx = fmaxf(mx, lg[i2]);
        mx = fmaxf(mx, __shfl_xor(mx, 16, 64));
        mx = fmaxf(mx, __shfl_xor(mx, 32, 64));
        const float mnew = fmaxf(m_run, mx);
        const float fsc  = __expf(m_run - mnew);
        m_run = mnew;
        float p16[16], rs = 0.f;
#pragma unroll
        for (int i2 = 0; i2 < 16; ++i2) { p16[i2] = __expf(lg[i2] - mnew); rs += p16[i2]; }
        rs += __shfl_xor(rs, 16, 64);
        rs += __shfl_xor(rs, 32, 64);
        l_run = l_run * fsc + rs;
        __builtin_amdgcn_sched_barrier(0);

        // ---- NOW issue next-iter prefetches (stage, bits, K overwrite) ----
        stage(p ^ 1, ktn);
        const unsigned long long bnxt = brow[ktn >> 6];
        LOADK(ktn);
        __builtin_amdgcn_sched_barrier(0);

        // ---- pack P -> wave-private swizzled LDS ----
#pragma unroll
        for (int t = 0; t < 4; ++t) {
            const unsigned int w0 = (unsigned int)f2bf(p16[4*t+0]) |
                                    ((unsigned int)f2bf(p16[4*t+1]) << 16);
            const unsigned int w1 = (unsigned int)f2bf(p16[4*t+2]) |
                                    ((unsigned int)f2bf(p16[4*t+3]) << 16);
            *(int2*)(pbase + roff + ((32*t + 8*g) ^ sw)) = make_int2((int)w0, (int)w1);
        }
        asm volatile("s_waitcnt lgkmcnt(0)" ::: "memory");
        __builtin_amdgcn_sched_barrier(0);
        const bf16x8 pa0 = *(const bf16x8*)(pbase + roff + ((     16*g) ^ sw));
        const bf16x8 pa1 = *(const bf16x8*)(pbase + roff + ((64 + 16*g) ^ sw));

        // ---- rescale O ----
        float fr[4];
#pragma unroll
        for (int j = 0; j < 4; ++j) fr[j] = __shfl(fsc, 4*g + j, 64);
#pragma unroll
        for (int j = 0; j < 4; ++j) {
            oa0[j] *= fr[j]; oa1[j] *= fr[j]; oa2[j] *= fr[j]; oa3[j] *= fr[j];
        }

        // ---- O += P.V (waits V(i), issued a full iter ago) ----
        __builtin_amdgcn_s_setprio(1);
        oa0 = MFMA16(pa0, v00, oa0); oa1 = MFMA16(pa0, v01, oa1);
        oa2 = MFMA16(pa0, v02, oa2); oa3 = MFMA16(pa0, v03, oa3);
        oa0 = MFMA16(pa1, v10, oa0); oa1 = MFMA16(pa1, v11, oa1);
        oa2 = MFMA16(pa1, v12, oa2); oa3 = MFMA16(pa1, v13, oa3);
        __builtin_amdgcn_s_setprio(0);
        __builtin_amdgcn_sched_barrier(0);

        // ---- issue next-iter V (after PV has read the old regs) ----
        LOADV(ktn);
        __builtin_amdgcn_sched_barrier(0);
        bcur = bnxt;
    }
#undef LOADK
#undef LOADV

    // ---- epilogue: normalize + write (b, q, h*64+dv) fp32 ----
    const float inv = 1.0f / l_run;
    float ir[4];
#pragma unroll
    for (int j = 0; j < 4; ++j) ir[j] = __shfl(inv, 4*g + j, 64);
    const int bb = bh >> 3, h = bh & 7;
    const f32x4 oav[4] = {oa0, oa1, oa2, oa3};
#pragma unroll
    for (int nt = 0; nt < 4; ++nt)
#pragma unroll
        for (int j = 0; j < 4; ++j)
            O[((size_t)(bb*NQ_ + q0 + 4*g + j))*DM_ + h*64 + 16*nt + r] = oav[nt][j] * ir[j];
}

// ---------------------------------------------------------------------------
extern "C" void kernel_launch(void* const* d_in, const int* in_sizes, int n_in,
                              void* d_out, int out_size, void* d_ws, size_t ws_size,
                              hipStream_t stream) {
    (void)in_sizes; (void)n_in; (void)out_size; (void)ws_size;

    const float* q    = (const float*)d_in[0];
    const float* k    = (const float*)d_in[1];
    const float* v    = (const float*)d_in[2];
    const float* attw = (const float*)d_in[3];
    const unsigned char* mask = (const unsigned char*)d_in[4];
    const float* Wq = (const float*)d_in[5];
    const float* bq = (const float*)d_in[6];
    const float* Wk = (const float*)d_in[7];
    const float* bk = (const float*)d_in[8];
    const float* Wv = (const float*)d_in[9];
    const float* bv = (const float*)d_in[10];
    const float* Wo = (const float*)d_in[11];
    const float* bo = (const float*)d_in[12];
    float* out = (float*)d_out;

    // ws (shorts): q_bf[NE] k_bf[NE] vT[NE] wt[8*WL] | bits[2Mi u64] | o_ws fp32
    const long long NE = (long long)B_*H_*NQ_*DK_;        // 4Mi
    unsigned short* q_bf = (unsigned short*)d_ws;
    unsigned short* k_bf = q_bf + NE;
    unsigned short* vT   = q_bf + 2*NE;
    unsigned short* wt   = q_bf + 3*NE;
    unsigned long long* bits = (unsigned long long*)(wt + 8LL*WL_);
    const long long NB = (long long)B_*H_*NQ_*NK_/64;     // 2Mi
    float* o_ws = (float*)(bits + NB);

    const dim3 blk(256);
    wprep<<<dim3(8, 8, 4), blk, 0, stream>>>(Wq, Wk, Wv, Wo, wt);
    conv_mask<<<dim3(2048), blk, 0, stream>>>(mask, bits);

    const dim3 gg(128, 8);
    gemm_split<0><<<gg, blk, 0, stream>>>(q, wt + 0*WL_, wt + 1*WL_, bq, q_bf, 0.125f);
    gemm_split<0><<<gg, blk, 0, stream>>>(k, wt + 2*WL_, wt + 3*WL_, bk, k_bf, 1.0f);
    gemm_split<1><<<gg, blk, 0, stream>>>(v, wt + 4*WL_, wt + 5*WL_, bv, vT, 1.0f);

    attn_mfma<<<dim3(NQ_/64, B_*H_), blk, 0, stream>>>(q_bf, k_bf, vT, attw, bits, o_ws);

    gemm_split<2><<<gg, blk, 0, stream>>>(o_ws, wt + 6*WL_, wt + 7*WL_, bo, out, 1.0f);
}